// Round 14
// baseline (377.508 us; speedup 1.0000x reference)
//
#include <hip/hip_runtime.h>
#include <math.h>

#define N_NODES 10000
#define N_EDGES 160000
#define HIDDEN 128
#define NUM_RBF 32
#define LATENT 64
#define N_GRAPHS 128
#define CUTOFF 5.0f
#define EPS 1e-8f

#define NBLK_N 157  // ceil(10000/64)

typedef __attribute__((ext_vector_type(8))) short short8;
typedef __attribute__((ext_vector_type(4))) float f32x4;
typedef unsigned short ushort_t;

__device__ __forceinline__ float fast_silu(float v) {
    return v * __builtin_amdgcn_rcpf(1.0f + __expf(-v));
}

__device__ __forceinline__ ushort_t f2bf(float f) {
    union { float f; unsigned u; } v;
    v.f = f;
    unsigned r = v.u + 0x7FFFu + ((v.u >> 16) & 1u);  // RNE
    return (ushort_t)(r >> 16);
}
__device__ __forceinline__ float bf2f(ushort_t u) {
    union { unsigned u; float f; } v;
    v.u = ((unsigned)u) << 16;
    return v.f;
}

// init (blocks < 15000): vec=0, dxb=0, pooled=0, deg=0, x=embed[z], x16=bf16(x)
// wprep (blocks >= 15000): all weight transposes to bf16
__global__ void init_kernel(const int* __restrict__ z, const float* __restrict__ embed,
                            float* __restrict__ x, ushort_t* __restrict__ x16,
                            float* __restrict__ vec, float* __restrict__ dxb,
                            float* __restrict__ pooled, int* __restrict__ deg,
                            const float* __restrict__ W1, const float* __restrict__ Wrbf,
                            const float* __restrict__ Wv, const float* __restrict__ Wo,
                            const float* __restrict__ Wvec2, const float* __restrict__ W_a,
                            const float* __restrict__ W_b, ushort_t* __restrict__ W1T,
                            ushort_t* __restrict__ WrbfT, ushort_t* __restrict__ WvT,
                            ushort_t* __restrict__ WoT, ushort_t* __restrict__ Wvec2T,
                            ushort_t* __restrict__ W_aT, ushort_t* __restrict__ W_bT) {
    if (blockIdx.x < 15000) {
        int i = blockIdx.x * 256 + threadIdx.x;
        if (i < N_NODES * 384) vec[i] = 0.0f;
        if (i < N_NODES * 128) {
            float v = embed[z[i >> 7] * 128 + (i & 127)];
            x[i] = v;
            x16[i] = f2bf(v);
            dxb[i] = 0.0f;
        }
        if (i < N_NODES) deg[i] = 0;
        if (i < N_GRAPHS * (LATENT + 1)) pooled[i] = 0.0f;
        return;
    }
    int i = (blockIdx.x - 15000) * 256 + threadIdx.x;
    if (i < 2 * 128 * 128) {
        int l = i >> 14;
        int n = (i & 16383) >> 7;
        int k = i & 127;
        W1T[i] = f2bf(W1[l * 16384 + k * 128 + n]);
        WvT[i] = f2bf(Wv[l * 16384 + k * 128 + n]);
        WoT[i] = f2bf(Wo[l * 16384 + k * 128 + n]);
    }
    if (i < 2 * 128 * 32) {
        int l = i >> 12;
        int n = (i & 4095) >> 5;
        int k = i & 31;
        WrbfT[i] = f2bf(Wrbf[l * 4096 + k * 128 + n]);
    }
    if (i < 128 * 128) {
        int n = i >> 7;
        int k = i & 127;
        Wvec2T[i] = f2bf(Wvec2[k * 128 + n]);
    }
    if (i < 128 * 256) {
        int n = i >> 8;
        int k = i & 255;
        W_aT[i] = f2bf(W_a[k * 128 + n]);
    }
    if (i < 80 * 128) {
        int n = i >> 7;
        int k = i & 127;
        W_bT[i] = (n < LATENT + 1) ? f2bf(W_b[k * (LATENT + 1) + n]) : (ushort_t)0;
    }
}

__global__ void hist_kernel(const int* __restrict__ dst, int* __restrict__ deg) {
    int e = blockIdx.x * blockDim.x + threadIdx.x;
    if (e < N_EDGES) atomicAdd(&deg[dst[e]], 1);
}

__global__ void prefix_kernel(const int* __restrict__ deg, int* __restrict__ cursor) {
    __shared__ int part[1024];
    const int ITEMS = 10;
    int t = threadIdx.x;
    int base = t * ITEMS;
    int local[ITEMS];
    int s = 0;
#pragma unroll
    for (int j = 0; j < ITEMS; j++) {
        int idx = base + j;
        int v = (idx < N_NODES) ? deg[idx] : 0;
        local[j] = s;
        s += v;
    }
    part[t] = s;
    __syncthreads();
    for (int off = 1; off < 1024; off <<= 1) {
        int v = (t >= off) ? part[t - off] : 0;
        __syncthreads();
        part[t] += v;
        __syncthreads();
    }
    int base_sum = (t > 0) ? part[t - 1] : 0;
#pragma unroll
    for (int j = 0; j < ITEMS; j++) {
        int idx = base + j;
        if (idx < N_NODES) cursor[idx] = base_sum + local[j];
    }
}

// scatter + geometry in PERMUTED order (r12 structure)
__global__ void scatter_geom_kernel(const int* __restrict__ ei, const float* __restrict__ pos,
                                    int* __restrict__ cursor, int* __restrict__ sperm,
                                    int* __restrict__ dperm, ushort_t* __restrict__ rbf16,
                                    float* __restrict__ dirn) {
    int e = blockIdx.x * blockDim.x + threadIdx.x;
    if (e >= N_EDGES) return;
    int s = ei[e];
    int t = ei[N_EDGES + e];
    int p = atomicAdd(&cursor[t], 1);
    sperm[p] = s;
    dperm[p] = t;

    float dx = pos[t * 3 + 0] - pos[s * 3 + 0];
    float dy = pos[t * 3 + 1] - pos[s * 3 + 1];
    float dz = pos[t * 3 + 2] - pos[s * 3 + 2];
    float r = sqrtf(dx * dx + dy * dy + dz * dz + EPS);
    float inv = 1.0f / r;
    dirn[p * 3 + 0] = dx * inv;
    dirn[p * 3 + 1] = dy * inv;
    dirn[p * 3 + 2] = dz * inv;

    float e5 = __expf(-CUTOFF);
    float span = 1.0f - e5;
    float b = (2.0f / NUM_RBF) * span;
    float beta = 1.0f / (b * b);
    float cut = (r < CUTOFF) ? 0.5f * (__cosf((float)M_PI * r / CUTOFF) + 1.0f) : 0.0f;
    float er = __expf(-r);
#pragma unroll
    for (int k = 0; k < NUM_RBF; k++) {
        float mean = e5 + span * ((float)k / (NUM_RBF - 1));
        float d = er - mean;
        rbf16[(size_t)p * 32 + k] = f2bf(cut * __expf(-beta * d * d));
    }
}

// ---------- device GEMM body (barrier-free, all LDS wave-private) ----------
// EPI bits: 1=bias, 2=add Cin, 4=silu, 8=bf16 out, 16=zero A after read, 64=also write bf16 mirror C16
template <int K, int EPI>
__device__ __forceinline__ void gemm_body(ushort_t* As, float* __restrict__ A,
                                          const ushort_t* __restrict__ WT,
                                          const float* __restrict__ bias,
                                          const float* __restrict__ Cin, float* __restrict__ C,
                                          ushort_t* __restrict__ C16, int M, int bx, int tid) {
    constexpr int STR = K + 8;
    int row0 = bx * 64;
    int w = tid >> 6;
    int lane = tid & 63;
    int c = lane & 15;
    int q = lane >> 4;
    int wr0 = w * 16;

    {
        int r = wr0 + (lane >> 2);
        int row = row0 + r;
        int segbase = (lane & 3) * (K / 4);
#pragma unroll
        for (int u = 0; u < K / 16; u++) {
            int k0 = segbase + u * 4;
            float4 v = make_float4(0.f, 0.f, 0.f, 0.f);
            if (row < M) v = *(const float4*)(A + (size_t)row * 128 + k0);
            ushort_t b4[4] = {f2bf(v.x), f2bf(v.y), f2bf(v.z), f2bf(v.w)};
            *(uint2*)(As + r * STR + k0) = *(uint2*)b4;
        }
        if ((EPI & 16) && row < M) {
            float4 z4 = make_float4(0.f, 0.f, 0.f, 0.f);
#pragma unroll
            for (int u = 0; u < 8; u++)
                *(float4*)(A + (size_t)row * 128 + (lane & 3) * 32 + u * 4) = z4;
        }
    }

    f32x4 acc[8] = {};
#pragma unroll
    for (int s = 0; s < K / 32; s++) {
        short8 af = *(const short8*)(As + (wr0 + c) * STR + s * 32 + q * 8);
#pragma unroll
        for (int t8 = 0; t8 < 8; t8++) {
            short8 bf = *(const short8*)(WT + (size_t)(t8 * 16 + c) * K + s * 32 + q * 8);
            acc[t8] = __builtin_amdgcn_mfma_f32_16x16x32_bf16(af, bf, acc[t8], 0, 0, 0);
        }
    }

    if (EPI & 8) {
#pragma unroll
        for (int t8 = 0; t8 < 8; t8++) {
#pragma unroll
            for (int r4 = 0; r4 < 4; r4++) {
                int lrow = wr0 + q * 4 + r4;
                As[lrow * STR + t8 * 16 + c] = f2bf(acc[t8][r4]);
            }
        }
#pragma unroll
        for (int i = 0; i < 4; i++) {
            int slot = lane + i * 64;
            int rl = slot >> 4;
            int c8 = slot & 15;
            int row = row0 + wr0 + rl;
            if (row < M)
                *(uint4*)((ushort_t*)C + (size_t)row * 128 + c8 * 8) =
                    *(uint4*)(As + (wr0 + rl) * STR + c8 * 8);
        }
    } else {
#pragma unroll
        for (int t8 = 0; t8 < 8; t8++) {
#pragma unroll
            for (int r4 = 0; r4 < 4; r4++) {
                int row = row0 + wr0 + q * 4 + r4;
                if (row < M) {
                    int col = t8 * 16 + c;
                    float o = acc[t8][r4];
                    if (EPI & 1) o += bias[col];
                    if (EPI & 2) o += Cin[(size_t)row * 128 + col];
                    if (EPI & 4) o = fast_silu(o);
                    C[(size_t)row * 128 + col] = o;
                    if (EPI & 64) C16[(size_t)row * 128 + col] = f2bf(o);
                }
            }
        }
    }
}

// combo1: blocks [0,157) Wo0 (x += dxb@Wo0, zero dxb, write x16) ; rest vmix16 = bf16(vec@Wv1)
__global__ __launch_bounds__(256, 4) void combo1_kernel(float* __restrict__ dxb,
                                                        const ushort_t* __restrict__ WoT0,
                                                        float* __restrict__ x,
                                                        ushort_t* __restrict__ x16,
                                                        float* __restrict__ vec,
                                                        const ushort_t* __restrict__ WvT1,
                                                        ushort_t* __restrict__ vmix16) {
    __shared__ ushort_t As[64 * 136];
    if (blockIdx.x < NBLK_N)
        gemm_body<128, 2 | 16 | 64>(As, dxb, WoT0, nullptr, x, x, x16, N_NODES, blockIdx.x,
                                    threadIdx.x);
    else
        gemm_body<128, 8>(As, vec, WvT1, nullptr, nullptr, (float*)vmix16, nullptr, N_NODES * 3,
                          blockIdx.x - NBLK_N, threadIdx.x);
}

// combo2: blocks [0,157) Wo1 (x += dxb@Wo1) ; rest vbuf = vec@Wvec2
__global__ __launch_bounds__(256, 4) void combo2_kernel(float* __restrict__ dxb,
                                                        const ushort_t* __restrict__ WoT1,
                                                        float* __restrict__ x,
                                                        float* __restrict__ vec,
                                                        const ushort_t* __restrict__ Wvec2T,
                                                        float* __restrict__ vbuf) {
    __shared__ ushort_t As[64 * 136];
    if (blockIdx.x < NBLK_N)
        gemm_body<128, 2>(As, dxb, WoT1, nullptr, x, x, nullptr, N_NODES, blockIdx.x,
                          threadIdx.x);
    else
        gemm_body<128, 0>(As, vec, Wvec2T, nullptr, nullptr, vbuf, nullptr, N_NODES * 3,
                          blockIdx.x - NBLK_N, threadIdx.x);
}

// ---------- fused readout, 16 rows/block (625 blocks) ----------
__global__ __launch_bounds__(256) void wa_pool_kernel(const float* __restrict__ x,
                                                      const float* __restrict__ vbuf,
                                                      const ushort_t* __restrict__ W_aT,
                                                      const float* __restrict__ b_a,
                                                      const ushort_t* __restrict__ W_bT,
                                                      const float* __restrict__ b_b,
                                                      const int* __restrict__ batch,
                                                      float* __restrict__ pooled) {
    __shared__ ushort_t As[16 * 264];
    __shared__ ushort_t A2[16 * 136];
    __shared__ int s_b[16];
    int tid = threadIdx.x;
    int row0 = blockIdx.x * 16;
    int w = tid >> 6;
    int lane = tid & 63;
    int c = lane & 15;
    int q = lane >> 4;

    if (tid < 16) s_b[tid] = batch[row0 + tid];
    {
        int r = tid >> 4;
        int seg = (tid & 15) * 16;
        int row = row0 + r;
#pragma unroll
        for (int u = 0; u < 4; u++) {
            int k0 = seg + u * 4;
            float4 v;
            if (k0 >= 128) {
                const float* vb = vbuf + (size_t)row * 384 + (k0 - 128);
                float4 va = *(const float4*)(vb);
                float4 vb2 = *(const float4*)(vb + 128);
                float4 vc = *(const float4*)(vb + 256);
                v.x = sqrtf(va.x * va.x + vb2.x * vb2.x + vc.x * vc.x + EPS);
                v.y = sqrtf(va.y * va.y + vb2.y * vb2.y + vc.y * vc.y + EPS);
                v.z = sqrtf(va.z * va.z + vb2.z * vb2.z + vc.z * vc.z + EPS);
                v.w = sqrtf(va.w * va.w + vb2.w * vb2.w + vc.w * vc.w + EPS);
            } else {
                v = *(const float4*)(x + (size_t)row * 128 + k0);
            }
            ushort_t b4[4] = {f2bf(v.x), f2bf(v.y), f2bf(v.z), f2bf(v.w)};
            *(uint2*)(As + r * 264 + k0) = *(uint2*)b4;
        }
    }
    __syncthreads();

    f32x4 acc[2] = {};
#pragma unroll
    for (int s = 0; s < 8; s++) {
        short8 af = *(const short8*)(As + c * 264 + s * 32 + q * 8);
#pragma unroll
        for (int i = 0; i < 2; i++) {
            int t8 = 2 * w + i;
            short8 bf = *(const short8*)(W_aT + (size_t)(t8 * 16 + c) * 256 + s * 32 + q * 8);
            acc[i] = __builtin_amdgcn_mfma_f32_16x16x32_bf16(af, bf, acc[i], 0, 0, 0);
        }
    }
#pragma unroll
    for (int i = 0; i < 2; i++) {
#pragma unroll
        for (int r4 = 0; r4 < 4; r4++) {
            int col = (2 * w + i) * 16 + c;
            A2[(q * 4 + r4) * 136 + col] = f2bf(fast_silu(acc[i][r4] + b_a[col]));
        }
    }
    __syncthreads();

    for (int t5 = w; t5 < 5; t5 += 4) {
        f32x4 acc2 = {};
#pragma unroll
        for (int s = 0; s < 4; s++) {
            short8 af = *(const short8*)(A2 + c * 136 + s * 32 + q * 8);
            short8 bf = *(const short8*)(W_bT + (size_t)(t5 * 16 + c) * 128 + s * 32 + q * 8);
            acc2 = __builtin_amdgcn_mfma_f32_16x16x32_bf16(af, bf, acc2, 0, 0, 0);
        }
        int col = t5 * 16 + c;
        if (col < LATENT + 1) {
            float bb = b_b[col];
#pragma unroll
            for (int r4 = 0; r4 < 4; r4++)
                atomicAdd(&pooled[s_b[q * 4 + r4] * (LATENT + 1) + col], acc2[r4] + bb);
        }
    }
}

// ------- fused edge kernel v14: early vmix prefetch, global index reads, transposed phi/filt -------
template <bool HASV>
__global__ __launch_bounds__(256, 4) void edge_fused(
    const ushort_t* __restrict__ rbf16, const ushort_t* __restrict__ WrbfT,
    const ushort_t* __restrict__ x16, const int* __restrict__ sperm,
    const int* __restrict__ dperm, const ushort_t* __restrict__ W1T,
    const float* __restrict__ dirn, const ushort_t* __restrict__ vmix,
    float* __restrict__ dxb, float* __restrict__ vec) {
    __shared__ __align__(16) char smem_raw[HASV ? 36864 : 18432];
    ushort_t* Ts = (ushort_t*)smem_raw;
    ushort_t* PhiT = (ushort_t*)smem_raw;
    ushort_t* FiltT = (ushort_t*)(smem_raw + 18432);
    __shared__ __align__(16) float s_dir4[256];

    int tid = threadIdx.x;
    int row0 = blockIdx.x * 64;
    int w = tid >> 6;
    int lane = tid & 63;
    int c = lane & 15;
    int q = lane >> 4;
    int wr0 = w * 16;  // wave-private row window
    int h = tid & 127;
    int half = tid >> 7;
    int rbeg = half * 32;

    // early vmix prefetch for reduction groups 0,1 — latency overlaps the MFMA phases
    ushort_t pr0[2][8], pr1[2][8], pr2[2][8];
    if (HASV) {
#pragma unroll
        for (int g = 0; g < 2; g++) {
#pragma unroll
            for (int j = 0; j < 8; j++) {
                int sidx = sperm[row0 + rbeg + g * 8 + j];
                const ushort_t* vm = vmix + (size_t)sidx * 384 + h;
                pr0[g][j] = vm[0];
                pr1[g][j] = vm[128];
                pr2[g][j] = vm[256];
            }
        }
    }

    if (w == 3) {
        const float* dp = dirn + (size_t)(row0 + lane) * 3;
        s_dir4[lane * 4 + 0] = dp[0];
        s_dir4[lane * 4 + 1] = dp[1];
        s_dir4[lane * 4 + 2] = dp[2];
        s_dir4[lane * 4 + 3] = 0.f;
    }

    // x16 scattered direct loads into registers (D-layout positions)
    int srow[4];
#pragma unroll
    for (int r = 0; r < 4; r++) srow[r] = sperm[row0 + wr0 + q * 4 + r];
    ushort_t xv[4][8];
#pragma unroll
    for (int r = 0; r < 4; r++) {
        const ushort_t* xp = x16 + (size_t)srow[r] * 128 + c;
#pragma unroll
        for (int t8 = 0; t8 < 8; t8++) xv[r][t8] = xp[t8 * 16];
    }

    // filt = rbf @ Wrbf (K=32), A-frags from global (coalesced, permuted order)
    f32x4 facc[8];
    {
        short8 af = *(const short8*)(rbf16 + (size_t)(row0 + wr0 + c) * 32 + q * 8);
#pragma unroll
        for (int t8 = 0; t8 < 8; t8++) {
            short8 bfr = *(const short8*)(WrbfT + (size_t)(t8 * 16 + c) * 32 + q * 8);
            f32x4 z = {};
            facc[t8] = __builtin_amdgcn_mfma_f32_16x16x32_bf16(af, bfr, z, 0, 0, 0);
        }
    }

    // t = filt * x -> Ts (normal layout, wave-private rows)
#pragma unroll
    for (int t8 = 0; t8 < 8; t8++) {
#pragma unroll
        for (int r = 0; r < 4; r++) {
            int row = wr0 + q * 4 + r;
            Ts[row * 136 + t8 * 16 + c] = f2bf(facc[t8][r] * bf2f(xv[r][t8]));
        }
    }

    // phi = silu(t @ W1) (K=128)
    f32x4 pacc[8] = {};
    const ushort_t* ap = Ts + (wr0 + c) * 136 + q * 8;
#pragma unroll
    for (int s = 0; s < 4; s++) {
        short8 af = *(const short8*)(ap + s * 32);
#pragma unroll
        for (int t8 = 0; t8 < 8; t8++) {
            short8 bfr = *(const short8*)(W1T + (size_t)(t8 * 16 + c) * 128 + s * 32 + q * 8);
            pacc[t8] = __builtin_amdgcn_mfma_f32_16x16x32_bf16(af, bfr, pacc[t8], 0, 0, 0);
        }
    }
    __syncthreads();  // all Ts reads complete before PhiT/FiltT overwrite

    // transposed packed writeback: PhiT[col][row] (uint2 = 4 rows)
#pragma unroll
    for (int t8 = 0; t8 < 8; t8++) {
        int col = t8 * 16 + c;
        ushort_t pb[4];
#pragma unroll
        for (int r = 0; r < 4; r++) pb[r] = f2bf(fast_silu(pacc[t8][r]));
        *(uint2*)(PhiT + col * 72 + wr0 + q * 4) = *(uint2*)pb;
        if (HASV) {
            ushort_t fb[4];
#pragma unroll
            for (int r = 0; r < 4; r++) fb[r] = f2bf(facc[t8][r]);
            *(uint2*)(FiltT + col * 72 + wr0 + q * 4) = *(uint2*)fb;
        }
    }
    __syncthreads();

    // segmented reduction: 256 threads = (col h, 32-row half); 2-deep prefetch ring
    float adx = 0.f, a0 = 0.f, a1 = 0.f, a2 = 0.f;
    int cur = dperm[row0 + rbeg];
#pragma unroll
    for (int g = 0; g < 4; g++) {
        int b = g & 1;
        float v0[8], v1[8], v2[8];
        if (HASV) {
#pragma unroll
            for (int j = 0; j < 8; j++) {
                v0[j] = bf2f(pr0[b][j]);
                v1[j] = bf2f(pr1[b][j]);
                v2[j] = bf2f(pr2[b][j]);
            }
            if (g < 2) {  // issue group g+2 into the just-freed slot
#pragma unroll
                for (int j = 0; j < 8; j++) {
                    int sidx = sperm[row0 + rbeg + (g + 2) * 8 + j];
                    const ushort_t* vm = vmix + (size_t)sidx * 384 + h;
                    pr0[b][j] = vm[0];
                    pr1[b][j] = vm[128];
                    pr2[b][j] = vm[256];
                }
            }
        }
        int da[8];
        *(uint4*)&da[0] = *(const uint4*)(dperm + row0 + rbeg + g * 8);
        *(uint4*)&da[4] = *(const uint4*)(dperm + row0 + rbeg + g * 8 + 4);
        ushort_t ph[8], fl[8];
        *(uint4*)ph = *(const uint4*)(PhiT + h * 72 + rbeg + g * 8);
        if (HASV) *(uint4*)fl = *(const uint4*)(FiltT + h * 72 + rbeg + g * 8);
#pragma unroll
        for (int j = 0; j < 8; j++) {
            int r = rbeg + g * 8 + j;
            int d = da[j];
            if (d != cur) {
                atomicAdd(&dxb[(size_t)cur * 128 + h], adx);
                atomicAdd(&vec[((size_t)cur * 3 + 0) * 128 + h], a0);
                atomicAdd(&vec[((size_t)cur * 3 + 1) * 128 + h], a1);
                atomicAdd(&vec[((size_t)cur * 3 + 2) * 128 + h], a2);
                cur = d;
                adx = a0 = a1 = a2 = 0.f;
            }
            float p = bf2f(ph[j]);
            float4 dd = *(const float4*)(s_dir4 + r * 4);
            adx += p;
            if (HASV) {
                float f = bf2f(fl[j]);
                a0 += v0[j] * f + p * dd.x;
                a1 += v1[j] * f + p * dd.y;
                a2 += v2[j] * f + p * dd.z;
            } else {
                a0 += p * dd.x;
                a1 += p * dd.y;
                a2 += p * dd.z;
            }
        }
    }
    atomicAdd(&dxb[(size_t)cur * 128 + h], adx);
    atomicAdd(&vec[((size_t)cur * 3 + 0) * 128 + h], a0);
    atomicAdd(&vec[((size_t)cur * 3 + 1) * 128 + h], a1);
    atomicAdd(&vec[((size_t)cur * 3 + 2) * 128 + h], a2);
}

__global__ void finalize_kernel(const float* __restrict__ pooled, float* __restrict__ out) {
    int i = blockIdx.x * blockDim.x + threadIdx.x;
    if (i >= N_GRAPHS * (LATENT + 1)) return;
    int g = i / (LATENT + 1);
    int k = i % (LATENT + 1);
    float v = pooled[i];
    if (k < LATENT) {
        out[g * LATENT + k] = v;
    } else {
        v = fminf(fmaxf(v, -10.0f), 2.0f);
        out[N_GRAPHS * LATENT + g] = v;
    }
}

extern "C" void kernel_launch(void* const* d_in, const int* in_sizes, int n_in,
                              void* d_out, int out_size, void* d_ws, size_t ws_size,
                              hipStream_t stream) {
    const int* z = (const int*)d_in[0];
    const float* pos = (const float*)d_in[1];
    const int* batch = (const int*)d_in[2];
    const int* ei = (const int*)d_in[3];
    const float* embed = (const float*)d_in[4];
    const float* W_rbf = (const float*)d_in[5];
    const float* W1 = (const float*)d_in[6];
    const float* Wo = (const float*)d_in[7];
    const float* Wv = (const float*)d_in[8];
    const float* Wvec2 = (const float*)d_in[10];
    const float* W_a = (const float*)d_in[11];
    const float* b_a = (const float*)d_in[12];
    const float* W_b = (const float*)d_in[13];
    const float* b_b = (const float*)d_in[14];
    float* out = (float*)d_out;

    const int* dsts = ei + N_EDGES;

    float* ws = (float*)d_ws;
    float* dirn = ws;                              // E*3 (permuted)
    float* x = dirn + (size_t)N_EDGES * 3;         // N*128
    float* vec = x + (size_t)N_NODES * 128;        // N*384
    float* vbuf = vec + (size_t)N_NODES * 384;     // N*384 (v2 fp32)
    float* dxb = vbuf + (size_t)N_NODES * 384;     // N*128
    float* pooled = dxb + (size_t)N_NODES * 128;   // 128*65 (+pad)
    ushort_t* x16 = (ushort_t*)(pooled + N_GRAPHS * (LATENT + 1) + 16);  // N*128
    ushort_t* rbf16 = x16 + (size_t)N_NODES * 128;    // E*32 (permuted)
    ushort_t* vmix16 = rbf16 + (size_t)N_EDGES * 32;  // N*384
    ushort_t* W1T = vmix16 + (size_t)N_NODES * 384;   // 2*16384
    ushort_t* WrbfT = W1T + 2 * 16384;                // 2*4096
    ushort_t* WvT = WrbfT + 2 * 4096;                 // 2*16384
    ushort_t* WoT = WvT + 2 * 16384;                  // 2*16384
    ushort_t* Wvec2T = WoT + 2 * 16384;               // 16384
    ushort_t* W_aT = Wvec2T + 16384;                  // 32768
    ushort_t* W_bT = W_aT + 32768;                    // 80*128
    int* ibase = (int*)(W_bT + 80 * 128);
    int* deg = ibase;               // N
    int* cursor = deg + N_NODES;    // N
    int* sperm = cursor + N_NODES;  // E
    int* dperm = sperm + N_EDGES;   // E

    init_kernel<<<15000 + 128, 256, 0, stream>>>(z, embed, x, x16, vec, dxb, pooled, deg, W1,
                                                 W_rbf, Wv, Wo, Wvec2, W_a, W_b, W1T, WrbfT, WvT,
                                                 WoT, Wvec2T, W_aT, W_bT);
    hist_kernel<<<(N_EDGES + 255) / 256, 256, 0, stream>>>(dsts, deg);
    prefix_kernel<<<1, 1024, 0, stream>>>(deg, cursor);
    scatter_geom_kernel<<<(N_EDGES + 255) / 256, 256, 0, stream>>>(ei, pos, cursor, sperm, dperm,
                                                                   rbf16, dirn);

    // ---- layer 0 (vec==0 -> vmix==0) ----
    edge_fused<false><<<N_EDGES / 64, 256, 0, stream>>>(rbf16, WrbfT, x16, sperm, dperm, W1T,
                                                        dirn, nullptr, dxb, vec);
    combo1_kernel<<<NBLK_N + (N_NODES * 3 + 63) / 64, 256, 0, stream>>>(dxb, WoT, x, x16, vec,
                                                                        WvT + 16384, vmix16);
    // ---- layer 1 ----
    edge_fused<true><<<N_EDGES / 64, 256, 0, stream>>>(rbf16, WrbfT + 4096, x16, sperm, dperm,
                                                       W1T + 16384, dirn, vmix16, dxb, vec);
    combo2_kernel<<<NBLK_N + (N_NODES * 3 + 63) / 64, 256, 0, stream>>>(dxb, WoT + 16384, x, vec,
                                                                        Wvec2T, vbuf);
    // ---- fused readout (16 rows/block) ----
    wa_pool_kernel<<<N_NODES / 16, 256, 0, stream>>>(x, vbuf, W_aT, b_a, W_bT, b_b, batch,
                                                     pooled);
    finalize_kernel<<<(N_GRAPHS * (LATENT + 1) + 255) / 256, 256, 0, stream>>>(pooled, out);
}

// Round 15
// 333.134 us; speedup vs baseline: 1.1332x; 1.1332x over previous
//
#include <hip/hip_runtime.h>
#include <math.h>

#define N_NODES 10000
#define N_EDGES 160000
#define HIDDEN 128
#define NUM_RBF 32
#define LATENT 64
#define N_GRAPHS 128
#define CUTOFF 5.0f
#define EPS 1e-8f

#define NBLK_N 157  // ceil(10000/64)

typedef __attribute__((ext_vector_type(8))) short short8;
typedef __attribute__((ext_vector_type(4))) float f32x4;
typedef unsigned short ushort_t;

__device__ __forceinline__ float fast_silu(float v) {
    return v * __builtin_amdgcn_rcpf(1.0f + __expf(-v));
}

__device__ __forceinline__ ushort_t f2bf(float f) {
    union { float f; unsigned u; } v;
    v.f = f;
    unsigned r = v.u + 0x7FFFu + ((v.u >> 16) & 1u);  // RNE
    return (ushort_t)(r >> 16);
}
__device__ __forceinline__ float bf2f(ushort_t u) {
    union { unsigned u; float f; } v;
    v.u = ((unsigned)u) << 16;
    return v.f;
}

// init (blocks < 15000): vec=0, dxb=0, pooled=0, deg=0, x=embed[z], x16=bf16(x)
// wprep (blocks >= 15000): all weight transposes to bf16
__global__ void init_kernel(const int* __restrict__ z, const float* __restrict__ embed,
                            float* __restrict__ x, ushort_t* __restrict__ x16,
                            float* __restrict__ vec, float* __restrict__ dxb,
                            float* __restrict__ pooled, int* __restrict__ deg,
                            const float* __restrict__ W1, const float* __restrict__ Wrbf,
                            const float* __restrict__ Wv, const float* __restrict__ Wo,
                            const float* __restrict__ Wvec2, const float* __restrict__ W_a,
                            const float* __restrict__ W_b, ushort_t* __restrict__ W1T,
                            ushort_t* __restrict__ WrbfT, ushort_t* __restrict__ WvT,
                            ushort_t* __restrict__ WoT, ushort_t* __restrict__ Wvec2T,
                            ushort_t* __restrict__ W_aT, ushort_t* __restrict__ W_bT) {
    if (blockIdx.x < 15000) {
        int i = blockIdx.x * 256 + threadIdx.x;
        if (i < N_NODES * 384) vec[i] = 0.0f;
        if (i < N_NODES * 128) {
            float v = embed[z[i >> 7] * 128 + (i & 127)];
            x[i] = v;
            x16[i] = f2bf(v);
            dxb[i] = 0.0f;
        }
        if (i < N_NODES) deg[i] = 0;
        if (i < N_GRAPHS * (LATENT + 1)) pooled[i] = 0.0f;
        return;
    }
    int i = (blockIdx.x - 15000) * 256 + threadIdx.x;
    if (i < 2 * 128 * 128) {
        int l = i >> 14;
        int n = (i & 16383) >> 7;
        int k = i & 127;
        W1T[i] = f2bf(W1[l * 16384 + k * 128 + n]);
        WvT[i] = f2bf(Wv[l * 16384 + k * 128 + n]);
        WoT[i] = f2bf(Wo[l * 16384 + k * 128 + n]);
    }
    if (i < 2 * 128 * 32) {
        int l = i >> 12;
        int n = (i & 4095) >> 5;
        int k = i & 31;
        WrbfT[i] = f2bf(Wrbf[l * 4096 + k * 128 + n]);
    }
    if (i < 128 * 128) {
        int n = i >> 7;
        int k = i & 127;
        Wvec2T[i] = f2bf(Wvec2[k * 128 + n]);
    }
    if (i < 128 * 256) {
        int n = i >> 8;
        int k = i & 255;
        W_aT[i] = f2bf(W_a[k * 128 + n]);
    }
    if (i < 80 * 128) {
        int n = i >> 7;
        int k = i & 127;
        W_bT[i] = (n < LATENT + 1) ? f2bf(W_b[k * (LATENT + 1) + n]) : (ushort_t)0;
    }
}

__global__ void hist_kernel(const int* __restrict__ dst, int* __restrict__ deg) {
    int e = blockIdx.x * blockDim.x + threadIdx.x;
    if (e < N_EDGES) atomicAdd(&deg[dst[e]], 1);
}

__global__ void prefix_kernel(const int* __restrict__ deg, int* __restrict__ cursor) {
    __shared__ int part[1024];
    const int ITEMS = 10;
    int t = threadIdx.x;
    int base = t * ITEMS;
    int local[ITEMS];
    int s = 0;
#pragma unroll
    for (int j = 0; j < ITEMS; j++) {
        int idx = base + j;
        int v = (idx < N_NODES) ? deg[idx] : 0;
        local[j] = s;
        s += v;
    }
    part[t] = s;
    __syncthreads();
    for (int off = 1; off < 1024; off <<= 1) {
        int v = (t >= off) ? part[t - off] : 0;
        __syncthreads();
        part[t] += v;
        __syncthreads();
    }
    int base_sum = (t > 0) ? part[t - 1] : 0;
#pragma unroll
    for (int j = 0; j < ITEMS; j++) {
        int idx = base + j;
        if (idx < N_NODES) cursor[idx] = base_sum + local[j];
    }
}

// scatter + geometry fused (permuted order writes)
__global__ void scatter_geom_kernel(const int* __restrict__ ei, const float* __restrict__ pos,
                                    int* __restrict__ cursor, int* __restrict__ sperm,
                                    int* __restrict__ dperm, ushort_t* __restrict__ rbf16,
                                    float* __restrict__ dirn) {
    int e = blockIdx.x * blockDim.x + threadIdx.x;
    if (e >= N_EDGES) return;
    int s = ei[e];
    int t = ei[N_EDGES + e];
    int p = atomicAdd(&cursor[t], 1);
    sperm[p] = s;
    dperm[p] = t;

    float dx = pos[t * 3 + 0] - pos[s * 3 + 0];
    float dy = pos[t * 3 + 1] - pos[s * 3 + 1];
    float dz = pos[t * 3 + 2] - pos[s * 3 + 2];
    float r = sqrtf(dx * dx + dy * dy + dz * dz + EPS);
    float inv = 1.0f / r;
    dirn[p * 3 + 0] = dx * inv;
    dirn[p * 3 + 1] = dy * inv;
    dirn[p * 3 + 2] = dz * inv;

    float e5 = __expf(-CUTOFF);
    float span = 1.0f - e5;
    float b = (2.0f / NUM_RBF) * span;
    float beta = 1.0f / (b * b);
    float cut = (r < CUTOFF) ? 0.5f * (__cosf((float)M_PI * r / CUTOFF) + 1.0f) : 0.0f;
    float er = __expf(-r);
#pragma unroll
    for (int k = 0; k < NUM_RBF; k++) {
        float mean = e5 + span * ((float)k / (NUM_RBF - 1));
        float d = er - mean;
        rbf16[(size_t)p * 32 + k] = f2bf(cut * __expf(-beta * d * d));
    }
}

// ---------- device GEMM body (barrier-free, all LDS wave-private) ----------
// EPI bits: 1=bias, 2=add Cin, 4=silu, 8=bf16 out, 16=zero A after read, 64=also write bf16 mirror C16
template <int K, int EPI>
__device__ __forceinline__ void gemm_body(ushort_t* As, float* __restrict__ A,
                                          const ushort_t* __restrict__ WT,
                                          const float* __restrict__ bias,
                                          const float* __restrict__ Cin, float* __restrict__ C,
                                          ushort_t* __restrict__ C16, int M, int bx, int tid) {
    constexpr int STR = K + 8;
    int row0 = bx * 64;
    int w = tid >> 6;
    int lane = tid & 63;
    int c = lane & 15;
    int q = lane >> 4;
    int wr0 = w * 16;

    {
        int r = wr0 + (lane >> 2);
        int row = row0 + r;
        int segbase = (lane & 3) * (K / 4);
#pragma unroll
        for (int u = 0; u < K / 16; u++) {
            int k0 = segbase + u * 4;
            float4 v = make_float4(0.f, 0.f, 0.f, 0.f);
            if (row < M) v = *(const float4*)(A + (size_t)row * 128 + k0);
            ushort_t b4[4] = {f2bf(v.x), f2bf(v.y), f2bf(v.z), f2bf(v.w)};
            *(uint2*)(As + r * STR + k0) = *(uint2*)b4;
        }
        if ((EPI & 16) && row < M) {
            float4 z4 = make_float4(0.f, 0.f, 0.f, 0.f);
#pragma unroll
            for (int u = 0; u < 8; u++)
                *(float4*)(A + (size_t)row * 128 + (lane & 3) * 32 + u * 4) = z4;
        }
    }

    f32x4 acc[8] = {};
#pragma unroll
    for (int s = 0; s < K / 32; s++) {
        short8 af = *(const short8*)(As + (wr0 + c) * STR + s * 32 + q * 8);
#pragma unroll
        for (int t8 = 0; t8 < 8; t8++) {
            short8 bf = *(const short8*)(WT + (size_t)(t8 * 16 + c) * K + s * 32 + q * 8);
            acc[t8] = __builtin_amdgcn_mfma_f32_16x16x32_bf16(af, bf, acc[t8], 0, 0, 0);
        }
    }

    if (EPI & 8) {
#pragma unroll
        for (int t8 = 0; t8 < 8; t8++) {
#pragma unroll
            for (int r4 = 0; r4 < 4; r4++) {
                int lrow = wr0 + q * 4 + r4;
                As[lrow * STR + t8 * 16 + c] = f2bf(acc[t8][r4]);
            }
        }
#pragma unroll
        for (int i = 0; i < 4; i++) {
            int slot = lane + i * 64;
            int rl = slot >> 4;
            int c8 = slot & 15;
            int row = row0 + wr0 + rl;
            if (row < M)
                *(uint4*)((ushort_t*)C + (size_t)row * 128 + c8 * 8) =
                    *(uint4*)(As + (wr0 + rl) * STR + c8 * 8);
        }
    } else {
#pragma unroll
        for (int t8 = 0; t8 < 8; t8++) {
#pragma unroll
            for (int r4 = 0; r4 < 4; r4++) {
                int row = row0 + wr0 + q * 4 + r4;
                if (row < M) {
                    int col = t8 * 16 + c;
                    float o = acc[t8][r4];
                    if (EPI & 1) o += bias[col];
                    if (EPI & 2) o += Cin[(size_t)row * 128 + col];
                    if (EPI & 4) o = fast_silu(o);
                    C[(size_t)row * 128 + col] = o;
                    if (EPI & 64) C16[(size_t)row * 128 + col] = f2bf(o);
                }
            }
        }
    }
}

// combo1: blocks [0,157) Wo0 (x += dxb@Wo0, zero dxb, write x16) ; rest vmix16 = bf16(vec@Wv1)
__global__ __launch_bounds__(256, 4) void combo1_kernel(float* __restrict__ dxb,
                                                        const ushort_t* __restrict__ WoT0,
                                                        float* __restrict__ x,
                                                        ushort_t* __restrict__ x16,
                                                        float* __restrict__ vec,
                                                        const ushort_t* __restrict__ WvT1,
                                                        ushort_t* __restrict__ vmix16) {
    __shared__ ushort_t As[64 * 136];
    if (blockIdx.x < NBLK_N)
        gemm_body<128, 2 | 16 | 64>(As, dxb, WoT0, nullptr, x, x, x16, N_NODES, blockIdx.x,
                                    threadIdx.x);
    else
        gemm_body<128, 8>(As, vec, WvT1, nullptr, nullptr, (float*)vmix16, nullptr, N_NODES * 3,
                          blockIdx.x - NBLK_N, threadIdx.x);
}

// combo2: blocks [0,157) Wo1 (x += dxb@Wo1) ; rest vbuf = vec@Wvec2
__global__ __launch_bounds__(256, 4) void combo2_kernel(float* __restrict__ dxb,
                                                        const ushort_t* __restrict__ WoT1,
                                                        float* __restrict__ x,
                                                        float* __restrict__ vec,
                                                        const ushort_t* __restrict__ Wvec2T,
                                                        float* __restrict__ vbuf) {
    __shared__ ushort_t As[64 * 136];
    if (blockIdx.x < NBLK_N)
        gemm_body<128, 2>(As, dxb, WoT1, nullptr, x, x, nullptr, N_NODES, blockIdx.x,
                          threadIdx.x);
    else
        gemm_body<128, 0>(As, vec, Wvec2T, nullptr, nullptr, vbuf, nullptr, N_NODES * 3,
                          blockIdx.x - NBLK_N, threadIdx.x);
}

// ---------- fused readout, 16 rows/block (625 blocks) ----------
__global__ __launch_bounds__(256) void wa_pool_kernel(const float* __restrict__ x,
                                                      const float* __restrict__ vbuf,
                                                      const ushort_t* __restrict__ W_aT,
                                                      const float* __restrict__ b_a,
                                                      const ushort_t* __restrict__ W_bT,
                                                      const float* __restrict__ b_b,
                                                      const int* __restrict__ batch,
                                                      float* __restrict__ pooled) {
    __shared__ ushort_t As[16 * 264];
    __shared__ ushort_t A2[16 * 136];
    __shared__ int s_b[16];
    int tid = threadIdx.x;
    int row0 = blockIdx.x * 16;
    int w = tid >> 6;
    int lane = tid & 63;
    int c = lane & 15;
    int q = lane >> 4;

    if (tid < 16) s_b[tid] = batch[row0 + tid];
    {
        int r = tid >> 4;
        int seg = (tid & 15) * 16;
        int row = row0 + r;
#pragma unroll
        for (int u = 0; u < 4; u++) {
            int k0 = seg + u * 4;
            float4 v;
            if (k0 >= 128) {
                const float* vb = vbuf + (size_t)row * 384 + (k0 - 128);
                float4 va = *(const float4*)(vb);
                float4 vb2 = *(const float4*)(vb + 128);
                float4 vc = *(const float4*)(vb + 256);
                v.x = sqrtf(va.x * va.x + vb2.x * vb2.x + vc.x * vc.x + EPS);
                v.y = sqrtf(va.y * va.y + vb2.y * vb2.y + vc.y * vc.y + EPS);
                v.z = sqrtf(va.z * va.z + vb2.z * vb2.z + vc.z * vc.z + EPS);
                v.w = sqrtf(va.w * va.w + vb2.w * vb2.w + vc.w * vc.w + EPS);
            } else {
                v = *(const float4*)(x + (size_t)row * 128 + k0);
            }
            ushort_t b4[4] = {f2bf(v.x), f2bf(v.y), f2bf(v.z), f2bf(v.w)};
            *(uint2*)(As + r * 264 + k0) = *(uint2*)b4;
        }
    }
    __syncthreads();

    f32x4 acc[2] = {};
#pragma unroll
    for (int s = 0; s < 8; s++) {
        short8 af = *(const short8*)(As + c * 264 + s * 32 + q * 8);
#pragma unroll
        for (int i = 0; i < 2; i++) {
            int t8 = 2 * w + i;
            short8 bf = *(const short8*)(W_aT + (size_t)(t8 * 16 + c) * 256 + s * 32 + q * 8);
            acc[i] = __builtin_amdgcn_mfma_f32_16x16x32_bf16(af, bf, acc[i], 0, 0, 0);
        }
    }
#pragma unroll
    for (int i = 0; i < 2; i++) {
#pragma unroll
        for (int r4 = 0; r4 < 4; r4++) {
            int col = (2 * w + i) * 16 + c;
            A2[(q * 4 + r4) * 136 + col] = f2bf(fast_silu(acc[i][r4] + b_a[col]));
        }
    }
    __syncthreads();

    for (int t5 = w; t5 < 5; t5 += 4) {
        f32x4 acc2 = {};
#pragma unroll
        for (int s = 0; s < 4; s++) {
            short8 af = *(const short8*)(A2 + c * 136 + s * 32 + q * 8);
            short8 bf = *(const short8*)(W_bT + (size_t)(t5 * 16 + c) * 128 + s * 32 + q * 8);
            acc2 = __builtin_amdgcn_mfma_f32_16x16x32_bf16(af, bf, acc2, 0, 0, 0);
        }
        int col = t5 * 16 + c;
        if (col < LATENT + 1) {
            float bb = b_b[col];
#pragma unroll
            for (int r4 = 0; r4 < 4; r4++)
                atomicAdd(&pooled[s_b[q * 4 + r4] * (LATENT + 1) + col], acc2[r4] + bb);
        }
    }
}

// ------- fused edge kernel (r12 structure): register x, transposed phi/filt, pipelined vmix gather -------
// L0 (HASV=false): 20KB LDS, launch_bounds min-waves 8 -> ~8 blocks/CU. L1: 4 blocks/CU.
template <bool HASV>
__global__ __launch_bounds__(256, HASV ? 4 : 8) void edge_fused(
    const ushort_t* __restrict__ rbf16, const ushort_t* __restrict__ WrbfT,
    const ushort_t* __restrict__ x16, const int* __restrict__ sperm,
    const int* __restrict__ dperm, const ushort_t* __restrict__ W1T,
    const float* __restrict__ dirn, const ushort_t* __restrict__ vmix,
    float* __restrict__ dxb, float* __restrict__ vec) {
    __shared__ __align__(16) char smem_raw[HASV ? 36864 : 18432];
    ushort_t* Ts = (ushort_t*)smem_raw;
    ushort_t* PhiT = (ushort_t*)smem_raw;
    ushort_t* FiltT = (ushort_t*)(smem_raw + 18432);
    __shared__ __align__(16) int s_src[64];
    __shared__ __align__(16) int s_dst[64];
    __shared__ __align__(16) float s_dir4[256];

    int tid = threadIdx.x;
    int row0 = blockIdx.x * 64;
    int w = tid >> 6;
    int lane = tid & 63;
    int c = lane & 15;
    int q = lane >> 4;
    int wr0 = w * 16;  // wave-private row window

    if (lane < 16) {
        s_src[wr0 + lane] = sperm[row0 + wr0 + lane];
        s_dst[wr0 + lane] = dperm[row0 + wr0 + lane];
    }
    if (w == 3) {
        const float* dp = dirn + (size_t)(row0 + lane) * 3;
        s_dir4[lane * 4 + 0] = dp[0];
        s_dir4[lane * 4 + 1] = dp[1];
        s_dir4[lane * 4 + 2] = dp[2];
        s_dir4[lane * 4 + 3] = 0.f;
    }

    // x16 scattered direct loads into registers (D-layout positions)
    int srow[4];
#pragma unroll
    for (int r = 0; r < 4; r++) srow[r] = sperm[row0 + wr0 + q * 4 + r];
    ushort_t xv[4][8];
#pragma unroll
    for (int r = 0; r < 4; r++) {
        const ushort_t* xp = x16 + (size_t)srow[r] * 128 + c;
#pragma unroll
        for (int t8 = 0; t8 < 8; t8++) xv[r][t8] = xp[t8 * 16];
    }

    // filt = rbf @ Wrbf (K=32), A-frags from global
    f32x4 facc[8];
    {
        short8 af = *(const short8*)(rbf16 + (size_t)(row0 + wr0 + c) * 32 + q * 8);
#pragma unroll
        for (int t8 = 0; t8 < 8; t8++) {
            short8 bfr = *(const short8*)(WrbfT + (size_t)(t8 * 16 + c) * 32 + q * 8);
            f32x4 z = {};
            facc[t8] = __builtin_amdgcn_mfma_f32_16x16x32_bf16(af, bfr, z, 0, 0, 0);
        }
    }

    // t = filt * x -> Ts (normal layout, wave-private rows)
#pragma unroll
    for (int t8 = 0; t8 < 8; t8++) {
#pragma unroll
        for (int r = 0; r < 4; r++) {
            int row = wr0 + q * 4 + r;
            Ts[row * 136 + t8 * 16 + c] = f2bf(facc[t8][r] * bf2f(xv[r][t8]));
        }
    }

    // phi = silu(t @ W1) (K=128)
    f32x4 pacc[8] = {};
    const ushort_t* ap = Ts + (wr0 + c) * 136 + q * 8;
#pragma unroll
    for (int s = 0; s < 4; s++) {
        short8 af = *(const short8*)(ap + s * 32);
#pragma unroll
        for (int t8 = 0; t8 < 8; t8++) {
            short8 bfr = *(const short8*)(W1T + (size_t)(t8 * 16 + c) * 128 + s * 32 + q * 8);
            pacc[t8] = __builtin_amdgcn_mfma_f32_16x16x32_bf16(af, bfr, pacc[t8], 0, 0, 0);
        }
    }
    __syncthreads();  // all Ts reads complete before PhiT/FiltT overwrite

    // transposed packed writeback: PhiT[col][row] (uint2 = 4 rows)
#pragma unroll
    for (int t8 = 0; t8 < 8; t8++) {
        int col = t8 * 16 + c;
        ushort_t pb[4];
#pragma unroll
        for (int r = 0; r < 4; r++) pb[r] = f2bf(fast_silu(pacc[t8][r]));
        *(uint2*)(PhiT + col * 72 + wr0 + q * 4) = *(uint2*)pb;
        if (HASV) {
            ushort_t fb[4];
#pragma unroll
            for (int r = 0; r < 4; r++) fb[r] = f2bf(facc[t8][r]);
            *(uint2*)(FiltT + col * 72 + wr0 + q * 4) = *(uint2*)fb;
        }
    }
    __syncthreads();

    // segmented reduction: 256 threads = (col h, 32-row half); vmix gather pipelined across groups
    int h = tid & 127;
    int half = tid >> 7;
    int rbeg = half * 32;
    float adx = 0.f, a0 = 0.f, a1 = 0.f, a2 = 0.f;

    float v0[2][8], v1[2][8], v2[2][8];
    if (HASV) {
        int sg[8];
        *(uint4*)&sg[0] = *(const uint4*)&s_src[rbeg];
        *(uint4*)&sg[4] = *(const uint4*)&s_src[rbeg + 4];
#pragma unroll
        for (int j = 0; j < 8; j++) {
            const ushort_t* vm = vmix + (size_t)sg[j] * 384 + h;
            v0[0][j] = bf2f(vm[0]);
            v1[0][j] = bf2f(vm[128]);
            v2[0][j] = bf2f(vm[256]);
        }
    }
    int cur = s_dst[rbeg];
#pragma unroll
    for (int g = 0; g < 4; g++) {
        int cb = g & 1, nb = cb ^ 1;
        if (HASV && g < 3) {
            int sg[8];
            *(uint4*)&sg[0] = *(const uint4*)&s_src[rbeg + (g + 1) * 8];
            *(uint4*)&sg[4] = *(const uint4*)&s_src[rbeg + (g + 1) * 8 + 4];
#pragma unroll
            for (int j = 0; j < 8; j++) {
                const ushort_t* vm = vmix + (size_t)sg[j] * 384 + h;
                v0[nb][j] = bf2f(vm[0]);
                v1[nb][j] = bf2f(vm[128]);
                v2[nb][j] = bf2f(vm[256]);
            }
        }
        int da[8];
        *(uint4*)&da[0] = *(const uint4*)&s_dst[rbeg + g * 8];
        *(uint4*)&da[4] = *(const uint4*)&s_dst[rbeg + g * 8 + 4];
        ushort_t ph[8], fl[8];
        *(uint4*)ph = *(const uint4*)(PhiT + h * 72 + rbeg + g * 8);
        if (HASV) *(uint4*)fl = *(const uint4*)(FiltT + h * 72 + rbeg + g * 8);
#pragma unroll
        for (int j = 0; j < 8; j++) {
            int r = rbeg + g * 8 + j;
            int d = da[j];
            if (d != cur) {
                atomicAdd(&dxb[(size_t)cur * 128 + h], adx);
                atomicAdd(&vec[((size_t)cur * 3 + 0) * 128 + h], a0);
                atomicAdd(&vec[((size_t)cur * 3 + 1) * 128 + h], a1);
                atomicAdd(&vec[((size_t)cur * 3 + 2) * 128 + h], a2);
                cur = d;
                adx = a0 = a1 = a2 = 0.f;
            }
            float p = bf2f(ph[j]);
            float4 dd = *(const float4*)(s_dir4 + r * 4);
            adx += p;
            if (HASV) {
                float f = bf2f(fl[j]);
                a0 += v0[cb][j] * f + p * dd.x;
                a1 += v1[cb][j] * f + p * dd.y;
                a2 += v2[cb][j] * f + p * dd.z;
            } else {
                a0 += p * dd.x;
                a1 += p * dd.y;
                a2 += p * dd.z;
            }
        }
    }
    atomicAdd(&dxb[(size_t)cur * 128 + h], adx);
    atomicAdd(&vec[((size_t)cur * 3 + 0) * 128 + h], a0);
    atomicAdd(&vec[((size_t)cur * 3 + 1) * 128 + h], a1);
    atomicAdd(&vec[((size_t)cur * 3 + 2) * 128 + h], a2);
}

__global__ void finalize_kernel(const float* __restrict__ pooled, float* __restrict__ out) {
    int i = blockIdx.x * blockDim.x + threadIdx.x;
    if (i >= N_GRAPHS * (LATENT + 1)) return;
    int g = i / (LATENT + 1);
    int k = i % (LATENT + 1);
    float v = pooled[i];
    if (k < LATENT) {
        out[g * LATENT + k] = v;
    } else {
        v = fminf(fmaxf(v, -10.0f), 2.0f);
        out[N_GRAPHS * LATENT + g] = v;
    }
}

extern "C" void kernel_launch(void* const* d_in, const int* in_sizes, int n_in,
                              void* d_out, int out_size, void* d_ws, size_t ws_size,
                              hipStream_t stream) {
    const int* z = (const int*)d_in[0];
    const float* pos = (const float*)d_in[1];
    const int* batch = (const int*)d_in[2];
    const int* ei = (const int*)d_in[3];
    const float* embed = (const float*)d_in[4];
    const float* W_rbf = (const float*)d_in[5];
    const float* W1 = (const float*)d_in[6];
    const float* Wo = (const float*)d_in[7];
    const float* Wv = (const float*)d_in[8];
    const float* Wvec2 = (const float*)d_in[10];
    const float* W_a = (const float*)d_in[11];
    const float* b_a = (const float*)d_in[12];
    const float* W_b = (const float*)d_in[13];
    const float* b_b = (const float*)d_in[14];
    float* out = (float*)d_out;

    const int* dsts = ei + N_EDGES;

    float* ws = (float*)d_ws;
    float* dirn = ws;                              // E*3 (permuted)
    float* x = dirn + (size_t)N_EDGES * 3;         // N*128
    float* vec = x + (size_t)N_NODES * 128;        // N*384
    float* vbuf = vec + (size_t)N_NODES * 384;     // N*384 (v2 fp32)
    float* dxb = vbuf + (size_t)N_NODES * 384;     // N*128
    float* pooled = dxb + (size_t)N_NODES * 128;   // 128*65 (+pad)
    ushort_t* x16 = (ushort_t*)(pooled + N_GRAPHS * (LATENT + 1) + 16);  // N*128
    ushort_t* rbf16 = x16 + (size_t)N_NODES * 128;    // E*32 (permuted)
    ushort_t* vmix16 = rbf16 + (size_t)N_EDGES * 32;  // N*384
    ushort_t* W1T = vmix16 + (size_t)N_NODES * 384;   // 2*16384
    ushort_t* WrbfT = W1T + 2 * 16384;                // 2*4096
    ushort_t* WvT = WrbfT + 2 * 4096;                 // 2*16384
    ushort_t* WoT = WvT + 2 * 16384;                  // 2*16384
    ushort_t* Wvec2T = WoT + 2 * 16384;               // 16384
    ushort_t* W_aT = Wvec2T + 16384;                  // 32768
    ushort_t* W_bT = W_aT + 32768;                    // 80*128
    int* ibase = (int*)(W_bT + 80 * 128);
    int* deg = ibase;               // N
    int* cursor = deg + N_NODES;    // N
    int* sperm = cursor + N_NODES;  // E
    int* dperm = sperm + N_EDGES;   // E

    init_kernel<<<15000 + 128, 256, 0, stream>>>(z, embed, x, x16, vec, dxb, pooled, deg, W1,
                                                 W_rbf, Wv, Wo, Wvec2, W_a, W_b, W1T, WrbfT, WvT,
                                                 WoT, Wvec2T, W_aT, W_bT);
    hist_kernel<<<(N_EDGES + 255) / 256, 256, 0, stream>>>(dsts, deg);
    prefix_kernel<<<1, 1024, 0, stream>>>(deg, cursor);
    scatter_geom_kernel<<<(N_EDGES + 255) / 256, 256, 0, stream>>>(ei, pos, cursor, sperm, dperm,
                                                                   rbf16, dirn);

    // ---- layer 0 (vec==0 -> vmix==0) ----
    edge_fused<false><<<N_EDGES / 64, 256, 0, stream>>>(rbf16, WrbfT, x16, sperm, dperm, W1T,
                                                        dirn, nullptr, dxb, vec);
    combo1_kernel<<<NBLK_N + (N_NODES * 3 + 63) / 64, 256, 0, stream>>>(dxb, WoT, x, x16, vec,
                                                                        WvT + 16384, vmix16);
    // ---- layer 1 ----
    edge_fused<true><<<N_EDGES / 64, 256, 0, stream>>>(rbf16, WrbfT + 4096, x16, sperm, dperm,
                                                       W1T + 16384, dirn, vmix16, dxb, vec);
    combo2_kernel<<<NBLK_N + (N_NODES * 3 + 63) / 64, 256, 0, stream>>>(dxb, WoT + 16384, x, vec,
                                                                        Wvec2T, vbuf);
    // ---- fused readout (16 rows/block) ----
    wa_pool_kernel<<<N_NODES / 16, 256, 0, stream>>>(x, vbuf, W_aT, b_a, W_bT, b_b, batch,
                                                     pooled);
    finalize_kernel<<<(N_GRAPHS * (LATENT + 1) + 255) / 256, 256, 0, stream>>>(pooled, out);
}

// Round 16
// 322.769 us; speedup vs baseline: 1.1696x; 1.0321x over previous
//
#include <hip/hip_runtime.h>
#include <math.h>

#define N_NODES 10000
#define N_EDGES 160000
#define HIDDEN 128
#define NUM_RBF 32
#define LATENT 64
#define N_GRAPHS 128
#define CUTOFF 5.0f
#define EPS 1e-8f

#define NBLK_N 157  // ceil(10000/64)

typedef __attribute__((ext_vector_type(8))) short short8;
typedef __attribute__((ext_vector_type(4))) float f32x4;
typedef unsigned short ushort_t;

__device__ __forceinline__ float fast_silu(float v) {
    return v * __builtin_amdgcn_rcpf(1.0f + __expf(-v));
}

__device__ __forceinline__ ushort_t f2bf(float f) {
    union { float f; unsigned u; } v;
    v.f = f;
    unsigned r = v.u + 0x7FFFu + ((v.u >> 16) & 1u);  // RNE
    return (ushort_t)(r >> 16);
}
__device__ __forceinline__ float bf2f(ushort_t u) {
    union { unsigned u; float f; } v;
    v.u = ((unsigned)u) << 16;
    return v.f;
}

// init (blocks < 15000): vec=0, dxb=0, pooled=0, deg=0, x=embed[z], x16=bf16(x)
// wprep (blocks >= 15000): all weight transposes to bf16
__global__ void init_kernel(const int* __restrict__ z, const float* __restrict__ embed,
                            float* __restrict__ x, ushort_t* __restrict__ x16,
                            float* __restrict__ vec, float* __restrict__ dxb,
                            float* __restrict__ pooled, int* __restrict__ deg,
                            const float* __restrict__ W1, const float* __restrict__ Wrbf,
                            const float* __restrict__ Wv, const float* __restrict__ Wo,
                            const float* __restrict__ Wvec2, const float* __restrict__ W_a,
                            const float* __restrict__ W_b, ushort_t* __restrict__ W1T,
                            ushort_t* __restrict__ WrbfT, ushort_t* __restrict__ WvT,
                            ushort_t* __restrict__ WoT, ushort_t* __restrict__ Wvec2T,
                            ushort_t* __restrict__ W_aT, ushort_t* __restrict__ W_bT) {
    if (blockIdx.x < 15000) {
        int i = blockIdx.x * 256 + threadIdx.x;
        if (i < N_NODES * 384) vec[i] = 0.0f;
        if (i < N_NODES * 128) {
            float v = embed[z[i >> 7] * 128 + (i & 127)];
            x[i] = v;
            x16[i] = f2bf(v);
            dxb[i] = 0.0f;
        }
        if (i < N_NODES) deg[i] = 0;
        if (i < N_GRAPHS * (LATENT + 1)) pooled[i] = 0.0f;
        return;
    }
    int i = (blockIdx.x - 15000) * 256 + threadIdx.x;
    if (i < 2 * 128 * 128) {
        int l = i >> 14;
        int n = (i & 16383) >> 7;
        int k = i & 127;
        W1T[i] = f2bf(W1[l * 16384 + k * 128 + n]);
        WvT[i] = f2bf(Wv[l * 16384 + k * 128 + n]);
        WoT[i] = f2bf(Wo[l * 16384 + k * 128 + n]);
    }
    if (i < 2 * 128 * 32) {
        int l = i >> 12;
        int n = (i & 4095) >> 5;
        int k = i & 31;
        WrbfT[i] = f2bf(Wrbf[l * 4096 + k * 128 + n]);
    }
    if (i < 128 * 128) {
        int n = i >> 7;
        int k = i & 127;
        Wvec2T[i] = f2bf(Wvec2[k * 128 + n]);
    }
    if (i < 128 * 256) {
        int n = i >> 8;
        int k = i & 255;
        W_aT[i] = f2bf(W_a[k * 128 + n]);
    }
    if (i < 80 * 128) {
        int n = i >> 7;
        int k = i & 127;
        W_bT[i] = (n < LATENT + 1) ? f2bf(W_b[k * (LATENT + 1) + n]) : (ushort_t)0;
    }
}

__global__ void hist_kernel(const int* __restrict__ dst, int* __restrict__ deg) {
    int e = blockIdx.x * blockDim.x + threadIdx.x;
    if (e < N_EDGES) atomicAdd(&deg[dst[e]], 1);
}

__global__ void prefix_kernel(const int* __restrict__ deg, int* __restrict__ cursor) {
    __shared__ int part[1024];
    const int ITEMS = 10;
    int t = threadIdx.x;
    int base = t * ITEMS;
    int local[ITEMS];
    int s = 0;
#pragma unroll
    for (int j = 0; j < ITEMS; j++) {
        int idx = base + j;
        int v = (idx < N_NODES) ? deg[idx] : 0;
        local[j] = s;
        s += v;
    }
    part[t] = s;
    __syncthreads();
    for (int off = 1; off < 1024; off <<= 1) {
        int v = (t >= off) ? part[t - off] : 0;
        __syncthreads();
        part[t] += v;
        __syncthreads();
    }
    int base_sum = (t > 0) ? part[t - 1] : 0;
#pragma unroll
    for (int j = 0; j < ITEMS; j++) {
        int idx = base + j;
        if (idx < N_NODES) cursor[idx] = base_sum + local[j];
    }
}

// scatter + geometry fused (permuted order writes)
__global__ void scatter_geom_kernel(const int* __restrict__ ei, const float* __restrict__ pos,
                                    int* __restrict__ cursor, int* __restrict__ sperm,
                                    int* __restrict__ dperm, ushort_t* __restrict__ rbf16,
                                    float* __restrict__ dirn) {
    int e = blockIdx.x * blockDim.x + threadIdx.x;
    if (e >= N_EDGES) return;
    int s = ei[e];
    int t = ei[N_EDGES + e];
    int p = atomicAdd(&cursor[t], 1);
    sperm[p] = s;
    dperm[p] = t;

    float dx = pos[t * 3 + 0] - pos[s * 3 + 0];
    float dy = pos[t * 3 + 1] - pos[s * 3 + 1];
    float dz = pos[t * 3 + 2] - pos[s * 3 + 2];
    float r = sqrtf(dx * dx + dy * dy + dz * dz + EPS);
    float inv = 1.0f / r;
    dirn[p * 3 + 0] = dx * inv;
    dirn[p * 3 + 1] = dy * inv;
    dirn[p * 3 + 2] = dz * inv;

    float e5 = __expf(-CUTOFF);
    float span = 1.0f - e5;
    float b = (2.0f / NUM_RBF) * span;
    float beta = 1.0f / (b * b);
    float cut = (r < CUTOFF) ? 0.5f * (__cosf((float)M_PI * r / CUTOFF) + 1.0f) : 0.0f;
    float er = __expf(-r);
#pragma unroll
    for (int k = 0; k < NUM_RBF; k++) {
        float mean = e5 + span * ((float)k / (NUM_RBF - 1));
        float d = er - mean;
        rbf16[(size_t)p * 32 + k] = f2bf(cut * __expf(-beta * d * d));
    }
}

// ---------- device GEMM body (barrier-free, all LDS wave-private) ----------
// EPI bits: 1=bias, 2=add Cin, 4=silu, 8=bf16 out, 16=zero A after read, 64=also write bf16 mirror C16
template <int K, int EPI>
__device__ __forceinline__ void gemm_body(ushort_t* As, float* __restrict__ A,
                                          const ushort_t* __restrict__ WT,
                                          const float* __restrict__ bias,
                                          const float* __restrict__ Cin, float* __restrict__ C,
                                          ushort_t* __restrict__ C16, int M, int bx, int tid) {
    constexpr int STR = K + 8;
    int row0 = bx * 64;
    int w = tid >> 6;
    int lane = tid & 63;
    int c = lane & 15;
    int q = lane >> 4;
    int wr0 = w * 16;

    {
        int r = wr0 + (lane >> 2);
        int row = row0 + r;
        int segbase = (lane & 3) * (K / 4);
#pragma unroll
        for (int u = 0; u < K / 16; u++) {
            int k0 = segbase + u * 4;
            float4 v = make_float4(0.f, 0.f, 0.f, 0.f);
            if (row < M) v = *(const float4*)(A + (size_t)row * 128 + k0);
            ushort_t b4[4] = {f2bf(v.x), f2bf(v.y), f2bf(v.z), f2bf(v.w)};
            *(uint2*)(As + r * STR + k0) = *(uint2*)b4;
        }
        if ((EPI & 16) && row < M) {
            float4 z4 = make_float4(0.f, 0.f, 0.f, 0.f);
#pragma unroll
            for (int u = 0; u < 8; u++)
                *(float4*)(A + (size_t)row * 128 + (lane & 3) * 32 + u * 4) = z4;
        }
    }

    f32x4 acc[8] = {};
#pragma unroll
    for (int s = 0; s < K / 32; s++) {
        short8 af = *(const short8*)(As + (wr0 + c) * STR + s * 32 + q * 8);
#pragma unroll
        for (int t8 = 0; t8 < 8; t8++) {
            short8 bf = *(const short8*)(WT + (size_t)(t8 * 16 + c) * K + s * 32 + q * 8);
            acc[t8] = __builtin_amdgcn_mfma_f32_16x16x32_bf16(af, bf, acc[t8], 0, 0, 0);
        }
    }

    if (EPI & 8) {
#pragma unroll
        for (int t8 = 0; t8 < 8; t8++) {
#pragma unroll
            for (int r4 = 0; r4 < 4; r4++) {
                int lrow = wr0 + q * 4 + r4;
                As[lrow * STR + t8 * 16 + c] = f2bf(acc[t8][r4]);
            }
        }
#pragma unroll
        for (int i = 0; i < 4; i++) {
            int slot = lane + i * 64;
            int rl = slot >> 4;
            int c8 = slot & 15;
            int row = row0 + wr0 + rl;
            if (row < M)
                *(uint4*)((ushort_t*)C + (size_t)row * 128 + c8 * 8) =
                    *(uint4*)(As + (wr0 + rl) * STR + c8 * 8);
        }
    } else {
#pragma unroll
        for (int t8 = 0; t8 < 8; t8++) {
#pragma unroll
            for (int r4 = 0; r4 < 4; r4++) {
                int row = row0 + wr0 + q * 4 + r4;
                if (row < M) {
                    int col = t8 * 16 + c;
                    float o = acc[t8][r4];
                    if (EPI & 1) o += bias[col];
                    if (EPI & 2) o += Cin[(size_t)row * 128 + col];
                    if (EPI & 4) o = fast_silu(o);
                    C[(size_t)row * 128 + col] = o;
                    if (EPI & 64) C16[(size_t)row * 128 + col] = f2bf(o);
                }
            }
        }
    }
}

// combo1: blocks [0,157) Wo0 (x += dxb@Wo0, zero dxb, write x16) ; rest vmix16 = bf16(vec@Wv1)
__global__ __launch_bounds__(256, 4) void combo1_kernel(float* __restrict__ dxb,
                                                        const ushort_t* __restrict__ WoT0,
                                                        float* __restrict__ x,
                                                        ushort_t* __restrict__ x16,
                                                        float* __restrict__ vec,
                                                        const ushort_t* __restrict__ WvT1,
                                                        ushort_t* __restrict__ vmix16) {
    __shared__ ushort_t As[64 * 136];
    if (blockIdx.x < NBLK_N)
        gemm_body<128, 2 | 16 | 64>(As, dxb, WoT0, nullptr, x, x, x16, N_NODES, blockIdx.x,
                                    threadIdx.x);
    else
        gemm_body<128, 8>(As, vec, WvT1, nullptr, nullptr, (float*)vmix16, nullptr, N_NODES * 3,
                          blockIdx.x - NBLK_N, threadIdx.x);
}

// combo2: blocks [0,157) Wo1 (x += dxb@Wo1) ; rest vbuf = vec@Wvec2
__global__ __launch_bounds__(256, 4) void combo2_kernel(float* __restrict__ dxb,
                                                        const ushort_t* __restrict__ WoT1,
                                                        float* __restrict__ x,
                                                        float* __restrict__ vec,
                                                        const ushort_t* __restrict__ Wvec2T,
                                                        float* __restrict__ vbuf) {
    __shared__ ushort_t As[64 * 136];
    if (blockIdx.x < NBLK_N)
        gemm_body<128, 2>(As, dxb, WoT1, nullptr, x, x, nullptr, N_NODES, blockIdx.x,
                          threadIdx.x);
    else
        gemm_body<128, 0>(As, vec, Wvec2T, nullptr, nullptr, vbuf, nullptr, N_NODES * 3,
                          blockIdx.x - NBLK_N, threadIdx.x);
}

// ---------- fused readout, 16 rows/block (625 blocks) ----------
__global__ __launch_bounds__(256) void wa_pool_kernel(const float* __restrict__ x,
                                                      const float* __restrict__ vbuf,
                                                      const ushort_t* __restrict__ W_aT,
                                                      const float* __restrict__ b_a,
                                                      const ushort_t* __restrict__ W_bT,
                                                      const float* __restrict__ b_b,
                                                      const int* __restrict__ batch,
                                                      float* __restrict__ pooled) {
    __shared__ ushort_t As[16 * 264];
    __shared__ ushort_t A2[16 * 136];
    __shared__ int s_b[16];
    int tid = threadIdx.x;
    int row0 = blockIdx.x * 16;
    int w = tid >> 6;
    int lane = tid & 63;
    int c = lane & 15;
    int q = lane >> 4;

    if (tid < 16) s_b[tid] = batch[row0 + tid];
    {
        int r = tid >> 4;
        int seg = (tid & 15) * 16;
        int row = row0 + r;
#pragma unroll
        for (int u = 0; u < 4; u++) {
            int k0 = seg + u * 4;
            float4 v;
            if (k0 >= 128) {
                const float* vb = vbuf + (size_t)row * 384 + (k0 - 128);
                float4 va = *(const float4*)(vb);
                float4 vb2 = *(const float4*)(vb + 128);
                float4 vc = *(const float4*)(vb + 256);
                v.x = sqrtf(va.x * va.x + vb2.x * vb2.x + vc.x * vc.x + EPS);
                v.y = sqrtf(va.y * va.y + vb2.y * vb2.y + vc.y * vc.y + EPS);
                v.z = sqrtf(va.z * va.z + vb2.z * vb2.z + vc.z * vc.z + EPS);
                v.w = sqrtf(va.w * va.w + vb2.w * vb2.w + vc.w * vc.w + EPS);
            } else {
                v = *(const float4*)(x + (size_t)row * 128 + k0);
            }
            ushort_t b4[4] = {f2bf(v.x), f2bf(v.y), f2bf(v.z), f2bf(v.w)};
            *(uint2*)(As + r * 264 + k0) = *(uint2*)b4;
        }
    }
    __syncthreads();

    f32x4 acc[2] = {};
#pragma unroll
    for (int s = 0; s < 8; s++) {
        short8 af = *(const short8*)(As + c * 264 + s * 32 + q * 8);
#pragma unroll
        for (int i = 0; i < 2; i++) {
            int t8 = 2 * w + i;
            short8 bf = *(const short8*)(W_aT + (size_t)(t8 * 16 + c) * 256 + s * 32 + q * 8);
            acc[i] = __builtin_amdgcn_mfma_f32_16x16x32_bf16(af, bf, acc[i], 0, 0, 0);
        }
    }
#pragma unroll
    for (int i = 0; i < 2; i++) {
#pragma unroll
        for (int r4 = 0; r4 < 4; r4++) {
            int col = (2 * w + i) * 16 + c;
            A2[(q * 4 + r4) * 136 + col] = f2bf(fast_silu(acc[i][r4] + b_a[col]));
        }
    }
    __syncthreads();

    for (int t5 = w; t5 < 5; t5 += 4) {
        f32x4 acc2 = {};
#pragma unroll
        for (int s = 0; s < 4; s++) {
            short8 af = *(const short8*)(A2 + c * 136 + s * 32 + q * 8);
            short8 bf = *(const short8*)(W_bT + (size_t)(t5 * 16 + c) * 128 + s * 32 + q * 8);
            acc2 = __builtin_amdgcn_mfma_f32_16x16x32_bf16(af, bf, acc2, 0, 0, 0);
        }
        int col = t5 * 16 + c;
        if (col < LATENT + 1) {
            float bb = b_b[col];
#pragma unroll
            for (int r4 = 0; r4 < 4; r4++)
                atomicAdd(&pooled[s_b[q * 4 + r4] * (LATENT + 1) + col], acc2[r4] + bb);
        }
    }
}

// ------- fused edge kernel (r12 structure): register x, transposed phi/filt, pipelined vmix gather -------
// L0 (HASV=false): 20KB LDS, min-waves 6 -> VGPR cap ~80 (no spill), ~6 blocks/CU. L1: 4 blocks/CU.
template <bool HASV>
__global__ __launch_bounds__(256, HASV ? 4 : 6) void edge_fused(
    const ushort_t* __restrict__ rbf16, const ushort_t* __restrict__ WrbfT,
    const ushort_t* __restrict__ x16, const int* __restrict__ sperm,
    const int* __restrict__ dperm, const ushort_t* __restrict__ W1T,
    const float* __restrict__ dirn, const ushort_t* __restrict__ vmix,
    float* __restrict__ dxb, float* __restrict__ vec) {
    __shared__ __align__(16) char smem_raw[HASV ? 36864 : 18432];
    ushort_t* Ts = (ushort_t*)smem_raw;
    ushort_t* PhiT = (ushort_t*)smem_raw;
    ushort_t* FiltT = (ushort_t*)(smem_raw + 18432);
    __shared__ __align__(16) int s_src[64];
    __shared__ __align__(16) int s_dst[64];
    __shared__ __align__(16) float s_dir4[256];

    int tid = threadIdx.x;
    int row0 = blockIdx.x * 64;
    int w = tid >> 6;
    int lane = tid & 63;
    int c = lane & 15;
    int q = lane >> 4;
    int wr0 = w * 16;  // wave-private row window

    if (lane < 16) {
        s_src[wr0 + lane] = sperm[row0 + wr0 + lane];
        s_dst[wr0 + lane] = dperm[row0 + wr0 + lane];
    }
    if (w == 3) {
        const float* dp = dirn + (size_t)(row0 + lane) * 3;
        s_dir4[lane * 4 + 0] = dp[0];
        s_dir4[lane * 4 + 1] = dp[1];
        s_dir4[lane * 4 + 2] = dp[2];
        s_dir4[lane * 4 + 3] = 0.f;
    }

    // x16 scattered direct loads into registers (D-layout positions)
    int srow[4];
#pragma unroll
    for (int r = 0; r < 4; r++) srow[r] = sperm[row0 + wr0 + q * 4 + r];
    ushort_t xv[4][8];
#pragma unroll
    for (int r = 0; r < 4; r++) {
        const ushort_t* xp = x16 + (size_t)srow[r] * 128 + c;
#pragma unroll
        for (int t8 = 0; t8 < 8; t8++) xv[r][t8] = xp[t8 * 16];
    }

    // filt = rbf @ Wrbf (K=32), A-frags from global
    f32x4 facc[8];
    {
        short8 af = *(const short8*)(rbf16 + (size_t)(row0 + wr0 + c) * 32 + q * 8);
#pragma unroll
        for (int t8 = 0; t8 < 8; t8++) {
            short8 bfr = *(const short8*)(WrbfT + (size_t)(t8 * 16 + c) * 32 + q * 8);
            f32x4 z = {};
            facc[t8] = __builtin_amdgcn_mfma_f32_16x16x32_bf16(af, bfr, z, 0, 0, 0);
        }
    }

    // t = filt * x -> Ts (normal layout, wave-private rows)
#pragma unroll
    for (int t8 = 0; t8 < 8; t8++) {
#pragma unroll
        for (int r = 0; r < 4; r++) {
            int row = wr0 + q * 4 + r;
            Ts[row * 136 + t8 * 16 + c] = f2bf(facc[t8][r] * bf2f(xv[r][t8]));
        }
    }

    // phi = silu(t @ W1) (K=128)
    f32x4 pacc[8] = {};
    const ushort_t* ap = Ts + (wr0 + c) * 136 + q * 8;
#pragma unroll
    for (int s = 0; s < 4; s++) {
        short8 af = *(const short8*)(ap + s * 32);
#pragma unroll
        for (int t8 = 0; t8 < 8; t8++) {
            short8 bfr = *(const short8*)(W1T + (size_t)(t8 * 16 + c) * 128 + s * 32 + q * 8);
            pacc[t8] = __builtin_amdgcn_mfma_f32_16x16x32_bf16(af, bfr, pacc[t8], 0, 0, 0);
        }
    }
    __syncthreads();  // all Ts reads complete before PhiT/FiltT overwrite

    // transposed packed writeback: PhiT[col][row] (uint2 = 4 rows)
#pragma unroll
    for (int t8 = 0; t8 < 8; t8++) {
        int col = t8 * 16 + c;
        ushort_t pb[4];
#pragma unroll
        for (int r = 0; r < 4; r++) pb[r] = f2bf(fast_silu(pacc[t8][r]));
        *(uint2*)(PhiT + col * 72 + wr0 + q * 4) = *(uint2*)pb;
        if (HASV) {
            ushort_t fb[4];
#pragma unroll
            for (int r = 0; r < 4; r++) fb[r] = f2bf(facc[t8][r]);
            *(uint2*)(FiltT + col * 72 + wr0 + q * 4) = *(uint2*)fb;
        }
    }
    __syncthreads();

    // segmented reduction: 256 threads = (col h, 32-row half); vmix gather pipelined across groups
    int h = tid & 127;
    int half = tid >> 7;
    int rbeg = half * 32;
    float adx = 0.f, a0 = 0.f, a1 = 0.f, a2 = 0.f;

    float v0[2][8], v1[2][8], v2[2][8];
    if (HASV) {
        int sg[8];
        *(uint4*)&sg[0] = *(const uint4*)&s_src[rbeg];
        *(uint4*)&sg[4] = *(const uint4*)&s_src[rbeg + 4];
#pragma unroll
        for (int j = 0; j < 8; j++) {
            const ushort_t* vm = vmix + (size_t)sg[j] * 384 + h;
            v0[0][j] = bf2f(vm[0]);
            v1[0][j] = bf2f(vm[128]);
            v2[0][j] = bf2f(vm[256]);
        }
    }
    int cur = s_dst[rbeg];
#pragma unroll
    for (int g = 0; g < 4; g++) {
        int cb = g & 1, nb = cb ^ 1;
        if (HASV && g < 3) {
            int sg[8];
            *(uint4*)&sg[0] = *(const uint4*)&s_src[rbeg + (g + 1) * 8];
            *(uint4*)&sg[4] = *(const uint4*)&s_src[rbeg + (g + 1) * 8 + 4];
#pragma unroll
            for (int j = 0; j < 8; j++) {
                const ushort_t* vm = vmix + (size_t)sg[j] * 384 + h;
                v0[nb][j] = bf2f(vm[0]);
                v1[nb][j] = bf2f(vm[128]);
                v2[nb][j] = bf2f(vm[256]);
            }
        }
        int da[8];
        *(uint4*)&da[0] = *(const uint4*)&s_dst[rbeg + g * 8];
        *(uint4*)&da[4] = *(const uint4*)&s_dst[rbeg + g * 8 + 4];
        ushort_t ph[8], fl[8];
        *(uint4*)ph = *(const uint4*)(PhiT + h * 72 + rbeg + g * 8);
        if (HASV) *(uint4*)fl = *(const uint4*)(FiltT + h * 72 + rbeg + g * 8);
#pragma unroll
        for (int j = 0; j < 8; j++) {
            int r = rbeg + g * 8 + j;
            int d = da[j];
            if (d != cur) {
                atomicAdd(&dxb[(size_t)cur * 128 + h], adx);
                atomicAdd(&vec[((size_t)cur * 3 + 0) * 128 + h], a0);
                atomicAdd(&vec[((size_t)cur * 3 + 1) * 128 + h], a1);
                atomicAdd(&vec[((size_t)cur * 3 + 2) * 128 + h], a2);
                cur = d;
                adx = a0 = a1 = a2 = 0.f;
            }
            float p = bf2f(ph[j]);
            float4 dd = *(const float4*)(s_dir4 + r * 4);
            adx += p;
            if (HASV) {
                float f = bf2f(fl[j]);
                a0 += v0[cb][j] * f + p * dd.x;
                a1 += v1[cb][j] * f + p * dd.y;
                a2 += v2[cb][j] * f + p * dd.z;
            } else {
                a0 += p * dd.x;
                a1 += p * dd.y;
                a2 += p * dd.z;
            }
        }
    }
    atomicAdd(&dxb[(size_t)cur * 128 + h], adx);
    atomicAdd(&vec[((size_t)cur * 3 + 0) * 128 + h], a0);
    atomicAdd(&vec[((size_t)cur * 3 + 1) * 128 + h], a1);
    atomicAdd(&vec[((size_t)cur * 3 + 2) * 128 + h], a2);
}

__global__ void finalize_kernel(const float* __restrict__ pooled, float* __restrict__ out) {
    int i = blockIdx.x * blockDim.x + threadIdx.x;
    if (i >= N_GRAPHS * (LATENT + 1)) return;
    int g = i / (LATENT + 1);
    int k = i % (LATENT + 1);
    float v = pooled[i];
    if (k < LATENT) {
        out[g * LATENT + k] = v;
    } else {
        v = fminf(fmaxf(v, -10.0f), 2.0f);
        out[N_GRAPHS * LATENT + g] = v;
    }
}

extern "C" void kernel_launch(void* const* d_in, const int* in_sizes, int n_in,
                              void* d_out, int out_size, void* d_ws, size_t ws_size,
                              hipStream_t stream) {
    const int* z = (const int*)d_in[0];
    const float* pos = (const float*)d_in[1];
    const int* batch = (const int*)d_in[2];
    const int* ei = (const int*)d_in[3];
    const float* embed = (const float*)d_in[4];
    const float* W_rbf = (const float*)d_in[5];
    const float* W1 = (const float*)d_in[6];
    const float* Wo = (const float*)d_in[7];
    const float* Wv = (const float*)d_in[8];
    const float* Wvec2 = (const float*)d_in[10];
    const float* W_a = (const float*)d_in[11];
    const float* b_a = (const float*)d_in[12];
    const float* W_b = (const float*)d_in[13];
    const float* b_b = (const float*)d_in[14];
    float* out = (float*)d_out;

    const int* dsts = ei + N_EDGES;

    float* ws = (float*)d_ws;
    float* dirn = ws;                              // E*3 (permuted)
    float* x = dirn + (size_t)N_EDGES * 3;         // N*128
    float* vec = x + (size_t)N_NODES * 128;        // N*384
    float* vbuf = vec + (size_t)N_NODES * 384;     // N*384 (v2 fp32)
    float* dxb = vbuf + (size_t)N_NODES * 384;     // N*128
    float* pooled = dxb + (size_t)N_NODES * 128;   // 128*65 (+pad)
    ushort_t* x16 = (ushort_t*)(pooled + N_GRAPHS * (LATENT + 1) + 16);  // N*128
    ushort_t* rbf16 = x16 + (size_t)N_NODES * 128;    // E*32 (permuted)
    ushort_t* vmix16 = rbf16 + (size_t)N_EDGES * 32;  // N*384
    ushort_t* W1T = vmix16 + (size_t)N_NODES * 384;   // 2*16384
    ushort_t* WrbfT = W1T + 2 * 16384;                // 2*4096
    ushort_t* WvT = WrbfT + 2 * 4096;                 // 2*16384
    ushort_t* WoT = WvT + 2 * 16384;                  // 2*16384
    ushort_t* Wvec2T = WoT + 2 * 16384;               // 16384
    ushort_t* W_aT = Wvec2T + 16384;                  // 32768
    ushort_t* W_bT = W_aT + 32768;                    // 80*128
    int* ibase = (int*)(W_bT + 80 * 128);
    int* deg = ibase;               // N
    int* cursor = deg + N_NODES;    // N
    int* sperm = cursor + N_NODES;  // E
    int* dperm = sperm + N_EDGES;   // E

    init_kernel<<<15000 + 128, 256, 0, stream>>>(z, embed, x, x16, vec, dxb, pooled, deg, W1,
                                                 W_rbf, Wv, Wo, Wvec2, W_a, W_b, W1T, WrbfT, WvT,
                                                 WoT, Wvec2T, W_aT, W_bT);
    hist_kernel<<<(N_EDGES + 255) / 256, 256, 0, stream>>>(dsts, deg);
    prefix_kernel<<<1, 1024, 0, stream>>>(deg, cursor);
    scatter_geom_kernel<<<(N_EDGES + 255) / 256, 256, 0, stream>>>(ei, pos, cursor, sperm, dperm,
                                                                   rbf16, dirn);

    // ---- layer 0 (vec==0 -> vmix==0) ----
    edge_fused<false><<<N_EDGES / 64, 256, 0, stream>>>(rbf16, WrbfT, x16, sperm, dperm, W1T,
                                                        dirn, nullptr, dxb, vec);
    combo1_kernel<<<NBLK_N + (N_NODES * 3 + 63) / 64, 256, 0, stream>>>(dxb, WoT, x, x16, vec,
                                                                        WvT + 16384, vmix16);
    // ---- layer 1 ----
    edge_fused<true><<<N_EDGES / 64, 256, 0, stream>>>(rbf16, WrbfT + 4096, x16, sperm, dperm,
                                                       W1T + 16384, dirn, vmix16, dxb, vec);
    combo2_kernel<<<NBLK_N + (N_NODES * 3 + 63) / 64, 256, 0, stream>>>(dxb, WoT + 16384, x, vec,
                                                                        Wvec2T, vbuf);
    // ---- fused readout (16 rows/block) ----
    wa_pool_kernel<<<N_NODES / 16, 256, 0, stream>>>(x, vbuf, W_aT, b_a, W_bT, b_b, batch,
                                                     pooled);
    finalize_kernel<<<(N_GRAPHS * (LATENT + 1) + 255) / 256, 256, 0, stream>>>(pooled, out);
}

// Round 17
// 317.492 us; speedup vs baseline: 1.1890x; 1.0166x over previous
//
#include <hip/hip_runtime.h>
#include <math.h>

#define N_NODES 10000
#define N_EDGES 160000
#define HIDDEN 128
#define NUM_RBF 32
#define LATENT 64
#define N_GRAPHS 128
#define CUTOFF 5.0f
#define EPS 1e-8f

#define NBLK_N 157   // ceil(10000/64)
#define INIT_V4 3750 // 960000 float4 of vec / 256
#define WPREP_B 128
#define HIST_B 625

typedef __attribute__((ext_vector_type(8))) short short8;
typedef __attribute__((ext_vector_type(4))) float f32x4;
typedef unsigned short ushort_t;

__device__ __forceinline__ float fast_silu(float v) {
    return v * __builtin_amdgcn_rcpf(1.0f + __expf(-v));
}

__device__ __forceinline__ ushort_t f2bf(float f) {
    union { float f; unsigned u; } v;
    v.f = f;
    unsigned r = v.u + 0x7FFFu + ((v.u >> 16) & 1u);  // RNE
    return (ushort_t)(r >> 16);
}
__device__ __forceinline__ float bf2f(ushort_t u) {
    union { unsigned u; float f; } v;
    v.u = ((unsigned)u) << 16;
    return v.f;
}

__global__ void zero_deg_kernel(int* __restrict__ deg) {
    int i = blockIdx.x * blockDim.x + threadIdx.x;
    if (i < N_NODES) deg[i] = 0;
}

// blocks [0, 3750): float4 zero vec/dxb/pooled, x=embed[z], x16=bf16(x)
// blocks [3750, 3878): weight transposes
// blocks [3878, 4503): hist (deg zeroed by preceding zero_deg_kernel)
__global__ void init_kernel(const int* __restrict__ z, const float* __restrict__ embed,
                            float* __restrict__ x, ushort_t* __restrict__ x16,
                            float* __restrict__ vec, float* __restrict__ dxb,
                            float* __restrict__ pooled, int* __restrict__ deg,
                            const int* __restrict__ dst,
                            const float* __restrict__ W1, const float* __restrict__ Wrbf,
                            const float* __restrict__ Wv, const float* __restrict__ Wo,
                            const float* __restrict__ Wvec2, const float* __restrict__ W_a,
                            const float* __restrict__ W_b, ushort_t* __restrict__ W1T,
                            ushort_t* __restrict__ WrbfT, ushort_t* __restrict__ WvT,
                            ushort_t* __restrict__ WoT, ushort_t* __restrict__ Wvec2T,
                            ushort_t* __restrict__ W_aT, ushort_t* __restrict__ W_bT) {
    if (blockIdx.x < INIT_V4) {
        int i = blockIdx.x * 256 + threadIdx.x;  // [0, 960000)
        float4 z4 = make_float4(0.f, 0.f, 0.f, 0.f);
        ((float4*)vec)[i] = z4;
        if (i < 320000) {  // x: 1.28M floats = 320000 float4; dxb same count
            int n = i >> 5;
            int k0 = (i & 31) * 4;
            float4 v = *(const float4*)(embed + (size_t)z[n] * 128 + k0);
            ((float4*)x)[i] = v;
            ushort_t b4[4] = {f2bf(v.x), f2bf(v.y), f2bf(v.z), f2bf(v.w)};
            *(uint2*)(x16 + (size_t)n * 128 + k0) = *(uint2*)b4;
            ((float4*)dxb)[i] = z4;
        }
        if (i < 2080) ((float4*)pooled)[i] = z4;  // 8320 floats
        return;
    }
    if (blockIdx.x < INIT_V4 + WPREP_B) {
        int i = (blockIdx.x - INIT_V4) * 256 + threadIdx.x;
        if (i < 2 * 128 * 128) {
            int l = i >> 14;
            int n = (i & 16383) >> 7;
            int k = i & 127;
            W1T[i] = f2bf(W1[l * 16384 + k * 128 + n]);
            WvT[i] = f2bf(Wv[l * 16384 + k * 128 + n]);
            WoT[i] = f2bf(Wo[l * 16384 + k * 128 + n]);
        }
        if (i < 2 * 128 * 32) {
            int l = i >> 12;
            int n = (i & 4095) >> 5;
            int k = i & 31;
            WrbfT[i] = f2bf(Wrbf[l * 4096 + k * 128 + n]);
        }
        if (i < 128 * 128) {
            int n = i >> 7;
            int k = i & 127;
            Wvec2T[i] = f2bf(Wvec2[k * 128 + n]);
        }
        if (i < 128 * 256) {
            int n = i >> 8;
            int k = i & 255;
            W_aT[i] = f2bf(W_a[k * 128 + n]);
        }
        if (i < 80 * 128) {
            int n = i >> 7;
            int k = i & 127;
            W_bT[i] = (n < LATENT + 1) ? f2bf(W_b[k * (LATENT + 1) + n]) : (ushort_t)0;
        }
        return;
    }
    int e = (blockIdx.x - INIT_V4 - WPREP_B) * 256 + threadIdx.x;
    if (e < N_EDGES) atomicAdd(&deg[dst[e]], 1);
}

__global__ void prefix_kernel(const int* __restrict__ deg, int* __restrict__ cursor) {
    __shared__ int part[1024];
    const int ITEMS = 10;
    int t = threadIdx.x;
    int base = t * ITEMS;
    int local[ITEMS];
    int s = 0;
#pragma unroll
    for (int j = 0; j < ITEMS; j++) {
        int idx = base + j;
        int v = (idx < N_NODES) ? deg[idx] : 0;
        local[j] = s;
        s += v;
    }
    part[t] = s;
    __syncthreads();
    for (int off = 1; off < 1024; off <<= 1) {
        int v = (t >= off) ? part[t - off] : 0;
        __syncthreads();
        part[t] += v;
        __syncthreads();
    }
    int base_sum = (t > 0) ? part[t - 1] : 0;
#pragma unroll
    for (int j = 0; j < ITEMS; j++) {
        int idx = base + j;
        if (idx < N_NODES) cursor[idx] = base_sum + local[j];
    }
}

// scatter + geometry fused (permuted order writes)
__global__ void scatter_geom_kernel(const int* __restrict__ ei, const float* __restrict__ pos,
                                    int* __restrict__ cursor, int* __restrict__ sperm,
                                    int* __restrict__ dperm, ushort_t* __restrict__ rbf16,
                                    float* __restrict__ dirn) {
    int e = blockIdx.x * blockDim.x + threadIdx.x;
    if (e >= N_EDGES) return;
    int s = ei[e];
    int t = ei[N_EDGES + e];
    int p = atomicAdd(&cursor[t], 1);
    sperm[p] = s;
    dperm[p] = t;

    float dx = pos[t * 3 + 0] - pos[s * 3 + 0];
    float dy = pos[t * 3 + 1] - pos[s * 3 + 1];
    float dz = pos[t * 3 + 2] - pos[s * 3 + 2];
    float r = sqrtf(dx * dx + dy * dy + dz * dz + EPS);
    float inv = 1.0f / r;
    dirn[p * 3 + 0] = dx * inv;
    dirn[p * 3 + 1] = dy * inv;
    dirn[p * 3 + 2] = dz * inv;

    float e5 = __expf(-CUTOFF);
    float span = 1.0f - e5;
    float b = (2.0f / NUM_RBF) * span;
    float beta = 1.0f / (b * b);
    float cut = (r < CUTOFF) ? 0.5f * (__cosf((float)M_PI * r / CUTOFF) + 1.0f) : 0.0f;
    float er = __expf(-r);
#pragma unroll
    for (int k = 0; k < NUM_RBF; k++) {
        float mean = e5 + span * ((float)k / (NUM_RBF - 1));
        float d = er - mean;
        rbf16[(size_t)p * 32 + k] = f2bf(cut * __expf(-beta * d * d));
    }
}

// ---------- device GEMM body (barrier-free, all LDS wave-private) ----------
// EPI bits: 1=bias, 2=add Cin, 4=silu, 8=bf16 out, 16=zero A after read, 64=also write bf16 mirror C16
template <int K, int EPI>
__device__ __forceinline__ void gemm_body(ushort_t* As, float* __restrict__ A,
                                          const ushort_t* __restrict__ WT,
                                          const float* __restrict__ bias,
                                          const float* __restrict__ Cin, float* __restrict__ C,
                                          ushort_t* __restrict__ C16, int M, int bx, int tid) {
    constexpr int STR = K + 8;
    int row0 = bx * 64;
    int w = tid >> 6;
    int lane = tid & 63;
    int c = lane & 15;
    int q = lane >> 4;
    int wr0 = w * 16;

    {
        int r = wr0 + (lane >> 2);
        int row = row0 + r;
        int segbase = (lane & 3) * (K / 4);
#pragma unroll
        for (int u = 0; u < K / 16; u++) {
            int k0 = segbase + u * 4;
            float4 v = make_float4(0.f, 0.f, 0.f, 0.f);
            if (row < M) v = *(const float4*)(A + (size_t)row * 128 + k0);
            ushort_t b4[4] = {f2bf(v.x), f2bf(v.y), f2bf(v.z), f2bf(v.w)};
            *(uint2*)(As + r * STR + k0) = *(uint2*)b4;
        }
        if ((EPI & 16) && row < M) {
            float4 z4 = make_float4(0.f, 0.f, 0.f, 0.f);
#pragma unroll
            for (int u = 0; u < 8; u++)
                *(float4*)(A + (size_t)row * 128 + (lane & 3) * 32 + u * 4) = z4;
        }
    }

    f32x4 acc[8] = {};
#pragma unroll
    for (int s = 0; s < K / 32; s++) {
        short8 af = *(const short8*)(As + (wr0 + c) * STR + s * 32 + q * 8);
#pragma unroll
        for (int t8 = 0; t8 < 8; t8++) {
            short8 bf = *(const short8*)(WT + (size_t)(t8 * 16 + c) * K + s * 32 + q * 8);
            acc[t8] = __builtin_amdgcn_mfma_f32_16x16x32_bf16(af, bf, acc[t8], 0, 0, 0);
        }
    }

    if (EPI & 8) {
#pragma unroll
        for (int t8 = 0; t8 < 8; t8++) {
#pragma unroll
            for (int r4 = 0; r4 < 4; r4++) {
                int lrow = wr0 + q * 4 + r4;
                As[lrow * STR + t8 * 16 + c] = f2bf(acc[t8][r4]);
            }
        }
#pragma unroll
        for (int i = 0; i < 4; i++) {
            int slot = lane + i * 64;
            int rl = slot >> 4;
            int c8 = slot & 15;
            int row = row0 + wr0 + rl;
            if (row < M)
                *(uint4*)((ushort_t*)C + (size_t)row * 128 + c8 * 8) =
                    *(uint4*)(As + (wr0 + rl) * STR + c8 * 8);
        }
    } else {
#pragma unroll
        for (int t8 = 0; t8 < 8; t8++) {
#pragma unroll
            for (int r4 = 0; r4 < 4; r4++) {
                int row = row0 + wr0 + q * 4 + r4;
                if (row < M) {
                    int col = t8 * 16 + c;
                    float o = acc[t8][r4];
                    if (EPI & 1) o += bias[col];
                    if (EPI & 2) o += Cin[(size_t)row * 128 + col];
                    if (EPI & 4) o = fast_silu(o);
                    C[(size_t)row * 128 + col] = o;
                    if (EPI & 64) C16[(size_t)row * 128 + col] = f2bf(o);
                }
            }
        }
    }
}

// combo1: blocks [0,157) Wo0 (x += dxb@Wo0, zero dxb, write x16) ; rest vmix16 = bf16(vec@Wv1)
__global__ __launch_bounds__(256, 4) void combo1_kernel(float* __restrict__ dxb,
                                                        const ushort_t* __restrict__ WoT0,
                                                        float* __restrict__ x,
                                                        ushort_t* __restrict__ x16,
                                                        float* __restrict__ vec,
                                                        const ushort_t* __restrict__ WvT1,
                                                        ushort_t* __restrict__ vmix16) {
    __shared__ ushort_t As[64 * 136];
    if (blockIdx.x < NBLK_N)
        gemm_body<128, 2 | 16 | 64>(As, dxb, WoT0, nullptr, x, x, x16, N_NODES, blockIdx.x,
                                    threadIdx.x);
    else
        gemm_body<128, 8>(As, vec, WvT1, nullptr, nullptr, (float*)vmix16, nullptr, N_NODES * 3,
                          blockIdx.x - NBLK_N, threadIdx.x);
}

// combo2: blocks [0,157) Wo1 (x += dxb@Wo1) ; rest vbuf = vec@Wvec2
__global__ __launch_bounds__(256, 4) void combo2_kernel(float* __restrict__ dxb,
                                                        const ushort_t* __restrict__ WoT1,
                                                        float* __restrict__ x,
                                                        float* __restrict__ vec,
                                                        const ushort_t* __restrict__ Wvec2T,
                                                        float* __restrict__ vbuf) {
    __shared__ ushort_t As[64 * 136];
    if (blockIdx.x < NBLK_N)
        gemm_body<128, 2>(As, dxb, WoT1, nullptr, x, x, nullptr, N_NODES, blockIdx.x,
                          threadIdx.x);
    else
        gemm_body<128, 0>(As, vec, Wvec2T, nullptr, nullptr, vbuf, nullptr, N_NODES * 3,
                          blockIdx.x - NBLK_N, threadIdx.x);
}

// ---------- fused readout, 16 rows/block (625 blocks) ----------
__global__ __launch_bounds__(256) void wa_pool_kernel(const float* __restrict__ x,
                                                      const float* __restrict__ vbuf,
                                                      const ushort_t* __restrict__ W_aT,
                                                      const float* __restrict__ b_a,
                                                      const ushort_t* __restrict__ W_bT,
                                                      const float* __restrict__ b_b,
                                                      const int* __restrict__ batch,
                                                      float* __restrict__ pooled) {
    __shared__ ushort_t As[16 * 264];
    __shared__ ushort_t A2[16 * 136];
    __shared__ int s_b[16];
    int tid = threadIdx.x;
    int row0 = blockIdx.x * 16;
    int w = tid >> 6;
    int lane = tid & 63;
    int c = lane & 15;
    int q = lane >> 4;

    if (tid < 16) s_b[tid] = batch[row0 + tid];
    {
        int r = tid >> 4;
        int seg = (tid & 15) * 16;
        int row = row0 + r;
#pragma unroll
        for (int u = 0; u < 4; u++) {
            int k0 = seg + u * 4;
            float4 v;
            if (k0 >= 128) {
                const float* vb = vbuf + (size_t)row * 384 + (k0 - 128);
                float4 va = *(const float4*)(vb);
                float4 vb2 = *(const float4*)(vb + 128);
                float4 vc = *(const float4*)(vb + 256);
                v.x = sqrtf(va.x * va.x + vb2.x * vb2.x + vc.x * vc.x + EPS);
                v.y = sqrtf(va.y * va.y + vb2.y * vb2.y + vc.y * vc.y + EPS);
                v.z = sqrtf(va.z * va.z + vb2.z * vb2.z + vc.z * vc.z + EPS);
                v.w = sqrtf(va.w * va.w + vb2.w * vb2.w + vc.w * vc.w + EPS);
            } else {
                v = *(const float4*)(x + (size_t)row * 128 + k0);
            }
            ushort_t b4[4] = {f2bf(v.x), f2bf(v.y), f2bf(v.z), f2bf(v.w)};
            *(uint2*)(As + r * 264 + k0) = *(uint2*)b4;
        }
    }
    __syncthreads();

    f32x4 acc[2] = {};
#pragma unroll
    for (int s = 0; s < 8; s++) {
        short8 af = *(const short8*)(As + c * 264 + s * 32 + q * 8);
#pragma unroll
        for (int i = 0; i < 2; i++) {
            int t8 = 2 * w + i;
            short8 bf = *(const short8*)(W_aT + (size_t)(t8 * 16 + c) * 256 + s * 32 + q * 8);
            acc[i] = __builtin_amdgcn_mfma_f32_16x16x32_bf16(af, bf, acc[i], 0, 0, 0);
        }
    }
#pragma unroll
    for (int i = 0; i < 2; i++) {
#pragma unroll
        for (int r4 = 0; r4 < 4; r4++) {
            int col = (2 * w + i) * 16 + c;
            A2[(q * 4 + r4) * 136 + col] = f2bf(fast_silu(acc[i][r4] + b_a[col]));
        }
    }
    __syncthreads();

    for (int t5 = w; t5 < 5; t5 += 4) {
        f32x4 acc2 = {};
#pragma unroll
        for (int s = 0; s < 4; s++) {
            short8 af = *(const short8*)(A2 + c * 136 + s * 32 + q * 8);
            short8 bf = *(const short8*)(W_bT + (size_t)(t5 * 16 + c) * 128 + s * 32 + q * 8);
            acc2 = __builtin_amdgcn_mfma_f32_16x16x32_bf16(af, bf, acc2, 0, 0, 0);
        }
        int col = t5 * 16 + c;
        if (col < LATENT + 1) {
            float bb = b_b[col];
#pragma unroll
            for (int r4 = 0; r4 < 4; r4++)
                atomicAdd(&pooled[s_b[q * 4 + r4] * (LATENT + 1) + col], acc2[r4] + bb);
        }
    }
}

// ------- fused edge kernel (r16 structure): register x, transposed phi/filt, pipelined vmix gather -------
template <bool HASV>
__global__ __launch_bounds__(256, HASV ? 4 : 6) void edge_fused(
    const ushort_t* __restrict__ rbf16, const ushort_t* __restrict__ WrbfT,
    const ushort_t* __restrict__ x16, const int* __restrict__ sperm,
    const int* __restrict__ dperm, const ushort_t* __restrict__ W1T,
    const float* __restrict__ dirn, const ushort_t* __restrict__ vmix,
    float* __restrict__ dxb, float* __restrict__ vec) {
    __shared__ __align__(16) char smem_raw[HASV ? 36864 : 18432];
    ushort_t* Ts = (ushort_t*)smem_raw;
    ushort_t* PhiT = (ushort_t*)smem_raw;
    ushort_t* FiltT = (ushort_t*)(smem_raw + 18432);
    __shared__ __align__(16) int s_src[64];
    __shared__ __align__(16) int s_dst[64];
    __shared__ __align__(16) float s_dir4[256];

    int tid = threadIdx.x;
    int row0 = blockIdx.x * 64;
    int w = tid >> 6;
    int lane = tid & 63;
    int c = lane & 15;
    int q = lane >> 4;
    int wr0 = w * 16;  // wave-private row window

    if (lane < 16) {
        s_src[wr0 + lane] = sperm[row0 + wr0 + lane];
        s_dst[wr0 + lane] = dperm[row0 + wr0 + lane];
    }
    if (w == 3) {
        const float* dp = dirn + (size_t)(row0 + lane) * 3;
        s_dir4[lane * 4 + 0] = dp[0];
        s_dir4[lane * 4 + 1] = dp[1];
        s_dir4[lane * 4 + 2] = dp[2];
        s_dir4[lane * 4 + 3] = 0.f;
    }

    // x16 scattered direct loads into registers (D-layout positions)
    int srow[4];
#pragma unroll
    for (int r = 0; r < 4; r++) srow[r] = sperm[row0 + wr0 + q * 4 + r];
    ushort_t xv[4][8];
#pragma unroll
    for (int r = 0; r < 4; r++) {
        const ushort_t* xp = x16 + (size_t)srow[r] * 128 + c;
#pragma unroll
        for (int t8 = 0; t8 < 8; t8++) xv[r][t8] = xp[t8 * 16];
    }

    // filt = rbf @ Wrbf (K=32), A-frags from global
    f32x4 facc[8];
    {
        short8 af = *(const short8*)(rbf16 + (size_t)(row0 + wr0 + c) * 32 + q * 8);
#pragma unroll
        for (int t8 = 0; t8 < 8; t8++) {
            short8 bfr = *(const short8*)(WrbfT + (size_t)(t8 * 16 + c) * 32 + q * 8);
            f32x4 z = {};
            facc[t8] = __builtin_amdgcn_mfma_f32_16x16x32_bf16(af, bfr, z, 0, 0, 0);
        }
    }

    // t = filt * x -> Ts (normal layout, wave-private rows)
#pragma unroll
    for (int t8 = 0; t8 < 8; t8++) {
#pragma unroll
        for (int r = 0; r < 4; r++) {
            int row = wr0 + q * 4 + r;
            Ts[row * 136 + t8 * 16 + c] = f2bf(facc[t8][r] * bf2f(xv[r][t8]));
        }
    }

    // phi = silu(t @ W1) (K=128)
    f32x4 pacc[8] = {};
    const ushort_t* ap = Ts + (wr0 + c) * 136 + q * 8;
#pragma unroll
    for (int s = 0; s < 4; s++) {
        short8 af = *(const short8*)(ap + s * 32);
#pragma unroll
        for (int t8 = 0; t8 < 8; t8++) {
            short8 bfr = *(const short8*)(W1T + (size_t)(t8 * 16 + c) * 128 + s * 32 + q * 8);
            pacc[t8] = __builtin_amdgcn_mfma_f32_16x16x32_bf16(af, bfr, pacc[t8], 0, 0, 0);
        }
    }
    __syncthreads();  // all Ts reads complete before PhiT/FiltT overwrite

    // transposed packed writeback: PhiT[col][row] (uint2 = 4 rows)
#pragma unroll
    for (int t8 = 0; t8 < 8; t8++) {
        int col = t8 * 16 + c;
        ushort_t pb[4];
#pragma unroll
        for (int r = 0; r < 4; r++) pb[r] = f2bf(fast_silu(pacc[t8][r]));
        *(uint2*)(PhiT + col * 72 + wr0 + q * 4) = *(uint2*)pb;
        if (HASV) {
            ushort_t fb[4];
#pragma unroll
            for (int r = 0; r < 4; r++) fb[r] = f2bf(facc[t8][r]);
            *(uint2*)(FiltT + col * 72 + wr0 + q * 4) = *(uint2*)fb;
        }
    }
    __syncthreads();

    // segmented reduction: 256 threads = (col h, 32-row half); vmix gather pipelined across groups
    int h = tid & 127;
    int half = tid >> 7;
    int rbeg = half * 32;
    float adx = 0.f, a0 = 0.f, a1 = 0.f, a2 = 0.f;

    float v0[2][8], v1[2][8], v2[2][8];
    if (HASV) {
        int sg[8];
        *(uint4*)&sg[0] = *(const uint4*)&s_src[rbeg];
        *(uint4*)&sg[4] = *(const uint4*)&s_src[rbeg + 4];
#pragma unroll
        for (int j = 0; j < 8; j++) {
            const ushort_t* vm = vmix + (size_t)sg[j] * 384 + h;
            v0[0][j] = bf2f(vm[0]);
            v1[0][j] = bf2f(vm[128]);
            v2[0][j] = bf2f(vm[256]);
        }
    }
    int cur = s_dst[rbeg];
#pragma unroll
    for (int g = 0; g < 4; g++) {
        int cb = g & 1, nb = cb ^ 1;
        if (HASV && g < 3) {
            int sg[8];
            *(uint4*)&sg[0] = *(const uint4*)&s_src[rbeg + (g + 1) * 8];
            *(uint4*)&sg[4] = *(const uint4*)&s_src[rbeg + (g + 1) * 8 + 4];
#pragma unroll
            for (int j = 0; j < 8; j++) {
                const ushort_t* vm = vmix + (size_t)sg[j] * 384 + h;
                v0[nb][j] = bf2f(vm[0]);
                v1[nb][j] = bf2f(vm[128]);
                v2[nb][j] = bf2f(vm[256]);
            }
        }
        int da[8];
        *(uint4*)&da[0] = *(const uint4*)&s_dst[rbeg + g * 8];
        *(uint4*)&da[4] = *(const uint4*)&s_dst[rbeg + g * 8 + 4];
        ushort_t ph[8], fl[8];
        *(uint4*)ph = *(const uint4*)(PhiT + h * 72 + rbeg + g * 8);
        if (HASV) *(uint4*)fl = *(const uint4*)(FiltT + h * 72 + rbeg + g * 8);
#pragma unroll
        for (int j = 0; j < 8; j++) {
            int r = rbeg + g * 8 + j;
            int d = da[j];
            if (d != cur) {
                atomicAdd(&dxb[(size_t)cur * 128 + h], adx);
                atomicAdd(&vec[((size_t)cur * 3 + 0) * 128 + h], a0);
                atomicAdd(&vec[((size_t)cur * 3 + 1) * 128 + h], a1);
                atomicAdd(&vec[((size_t)cur * 3 + 2) * 128 + h], a2);
                cur = d;
                adx = a0 = a1 = a2 = 0.f;
            }
            float p = bf2f(ph[j]);
            float4 dd = *(const float4*)(s_dir4 + r * 4);
            adx += p;
            if (HASV) {
                float f = bf2f(fl[j]);
                a0 += v0[cb][j] * f + p * dd.x;
                a1 += v1[cb][j] * f + p * dd.y;
                a2 += v2[cb][j] * f + p * dd.z;
            } else {
                a0 += p * dd.x;
                a1 += p * dd.y;
                a2 += p * dd.z;
            }
        }
    }
    atomicAdd(&dxb[(size_t)cur * 128 + h], adx);
    atomicAdd(&vec[((size_t)cur * 3 + 0) * 128 + h], a0);
    atomicAdd(&vec[((size_t)cur * 3 + 1) * 128 + h], a1);
    atomicAdd(&vec[((size_t)cur * 3 + 2) * 128 + h], a2);
}

__global__ void finalize_kernel(const float* __restrict__ pooled, float* __restrict__ out) {
    int i = blockIdx.x * blockDim.x + threadIdx.x;
    if (i >= N_GRAPHS * (LATENT + 1)) return;
    int g = i / (LATENT + 1);
    int k = i % (LATENT + 1);
    float v = pooled[i];
    if (k < LATENT) {
        out[g * LATENT + k] = v;
    } else {
        v = fminf(fmaxf(v, -10.0f), 2.0f);
        out[N_GRAPHS * LATENT + g] = v;
    }
}

extern "C" void kernel_launch(void* const* d_in, const int* in_sizes, int n_in,
                              void* d_out, int out_size, void* d_ws, size_t ws_size,
                              hipStream_t stream) {
    const int* z = (const int*)d_in[0];
    const float* pos = (const float*)d_in[1];
    const int* batch = (const int*)d_in[2];
    const int* ei = (const int*)d_in[3];
    const float* embed = (const float*)d_in[4];
    const float* W_rbf = (const float*)d_in[5];
    const float* W1 = (const float*)d_in[6];
    const float* Wo = (const float*)d_in[7];
    const float* Wv = (const float*)d_in[8];
    const float* Wvec2 = (const float*)d_in[10];
    const float* W_a = (const float*)d_in[11];
    const float* b_a = (const float*)d_in[12];
    const float* W_b = (const float*)d_in[13];
    const float* b_b = (const float*)d_in[14];
    float* out = (float*)d_out;

    const int* dsts = ei + N_EDGES;

    float* ws = (float*)d_ws;
    float* dirn = ws;                              // E*3 (permuted)
    float* x = dirn + (size_t)N_EDGES * 3;         // N*128
    float* vec = x + (size_t)N_NODES * 128;        // N*384
    float* vbuf = vec + (size_t)N_NODES * 384;     // N*384 (v2 fp32)
    float* dxb = vbuf + (size_t)N_NODES * 384;     // N*128
    float* pooled = dxb + (size_t)N_NODES * 128;   // 128*65 (+pad)
    ushort_t* x16 = (ushort_t*)(pooled + N_GRAPHS * (LATENT + 1) + 16);  // N*128
    ushort_t* rbf16 = x16 + (size_t)N_NODES * 128;    // E*32 (permuted)
    ushort_t* vmix16 = rbf16 + (size_t)N_EDGES * 32;  // N*384
    ushort_t* W1T = vmix16 + (size_t)N_NODES * 384;   // 2*16384
    ushort_t* WrbfT = W1T + 2 * 16384;                // 2*4096
    ushort_t* WvT = WrbfT + 2 * 4096;                 // 2*16384
    ushort_t* WoT = WvT + 2 * 16384;                  // 2*16384
    ushort_t* Wvec2T = WoT + 2 * 16384;               // 16384
    ushort_t* W_aT = Wvec2T + 16384;                  // 32768
    ushort_t* W_bT = W_aT + 32768;                    // 80*128
    int* ibase = (int*)(W_bT + 80 * 128);
    int* deg = ibase;               // N
    int* cursor = deg + N_NODES;    // N
    int* sperm = cursor + N_NODES;  // E
    int* dperm = sperm + N_EDGES;   // E

    zero_deg_kernel<<<(N_NODES + 255) / 256, 256, 0, stream>>>(deg);
    init_kernel<<<INIT_V4 + WPREP_B + HIST_B, 256, 0, stream>>>(
        z, embed, x, x16, vec, dxb, pooled, deg, dsts, W1, W_rbf, Wv, Wo, Wvec2, W_a, W_b, W1T,
        WrbfT, WvT, WoT, Wvec2T, W_aT, W_bT);
    prefix_kernel<<<1, 1024, 0, stream>>>(deg, cursor);
    scatter_geom_kernel<<<(N_EDGES + 255) / 256, 256, 0, stream>>>(ei, pos, cursor, sperm, dperm,
                                                                   rbf16, dirn);

    // ---- layer 0 (vec==0 -> vmix==0) ----
    edge_fused<false><<<N_EDGES / 64, 256, 0, stream>>>(rbf16, WrbfT, x16, sperm, dperm, W1T,
                                                        dirn, nullptr, dxb, vec);
    combo1_kernel<<<NBLK_N + (N_NODES * 3 + 63) / 64, 256, 0, stream>>>(dxb, WoT, x, x16, vec,
                                                                        WvT + 16384, vmix16);
    // ---- layer 1 ----
    edge_fused<true><<<N_EDGES / 64, 256, 0, stream>>>(rbf16, WrbfT + 4096, x16, sperm, dperm,
                                                       W1T + 16384, dirn, vmix16, dxb, vec);
    combo2_kernel<<<NBLK_N + (N_NODES * 3 + 63) / 64, 256, 0, stream>>>(dxb, WoT + 16384, x, vec,
                                                                        Wvec2T, vbuf);
    // ---- fused readout (16 rows/block) ----
    wa_pool_kernel<<<N_NODES / 16, 256, 0, stream>>>(x, vbuf, W_aT, b_a, W_bT, b_b, batch,
                                                     pooled);
    finalize_kernel<<<(N_GRAPHS * (LATENT + 1) + 255) / 256, 256, 0, stream>>>(pooled, out);
}